// Round 1
// 250.361 us; speedup vs baseline: 1.1158x; 1.1158x over previous
//
#include <hip/hip_runtime.h>

constexpr int T = 1024;
constexpr int B = 64;
constexpr int V = 512;
constexpr int L = 256;
constexpr int S = 2 * L + 1;   // 513
constexpr int C = 16;          // scan chunk rows (128 B/lane, register-resident)

typedef float f32x4 __attribute__((ext_vector_type(4)));

__device__ __forceinline__ unsigned short f2bf(float f) {  // RNE
    unsigned u = __float_as_uint(f);
    u += 0x7fffu + ((u >> 16) & 1u);
    return (unsigned short)(u >> 16);
}

__device__ __forceinline__ float lane_bcast(float v, int i) {
    return __uint_as_float((unsigned)__builtin_amdgcn_readlane((int)__float_as_uint(v), i));
}

// ws layout (batch-major):
// [0]      lse_rows : B*T floats (256 KB)   [b*T+t]
// [256K]   blankU   : B*T floats (256 KB)   [b*T+t]  exp(blank logit)
// [512K]   offsets  : B ints
// [1M]     packedU  : B*T*256 bf16 (32 MB)  [(b*T+t)*256+j] exp(label logits)

__global__ __launch_bounds__(64) void offsets_kernel(
    const int* __restrict__ label_lens, int* __restrict__ offsets)
{
    int lane = threadIdx.x;
    int v = (lane < B) ? label_lens[lane] : 0;
    int x = v;
#pragma unroll
    for (int o = 1; o < 64; o <<= 1) {
        int y = __shfl_up(x, o, 64);
        if (lane >= o) x += y;
    }
    if (lane < B) offsets[lane] = x - v;
}

// ---------------------------------------------------------------------------
// Setup: one wave per TWO (t,b) rows. exp the rows once; emit row-lse + bf16
// exp(label logits) + blank, all in BATCH-MAJOR layout.
// ---------------------------------------------------------------------------
__global__ __launch_bounds__(256) void setup_kernel(
    const float* __restrict__ acts, const int* __restrict__ labels,
    const int* __restrict__ label_lens, const int* __restrict__ offsets,
    float* __restrict__ lse_rows, unsigned short* __restrict__ packedU,
    float* __restrict__ blankU)
{
    __shared__ float rows[4][2][V];          // 16 KB
    const int w    = threadIdx.x >> 6;
    const int lane = threadIdx.x & 63;
    const int rbase = (blockIdx.x * 4 + w) * 2;     // rows rbase, rbase+1
    const f32x4* p = (const f32x4*)(acts + (size_t)rbase * V);

    f32x4 xa0 = __builtin_nontemporal_load(p + lane);
    f32x4 xa1 = __builtin_nontemporal_load(p + lane + 64);
    f32x4 xb0 = __builtin_nontemporal_load(p + lane + 128);
    f32x4 xb1 = __builtin_nontemporal_load(p + lane + 192);
    f32x4 ea0, ea1, eb0, eb1;
    ea0.x=__expf(xa0.x); ea0.y=__expf(xa0.y); ea0.z=__expf(xa0.z); ea0.w=__expf(xa0.w);
    ea1.x=__expf(xa1.x); ea1.y=__expf(xa1.y); ea1.z=__expf(xa1.z); ea1.w=__expf(xa1.w);
    eb0.x=__expf(xb0.x); eb0.y=__expf(xb0.y); eb0.z=__expf(xb0.z); eb0.w=__expf(xb0.w);
    eb1.x=__expf(xb1.x); eb1.y=__expf(xb1.y); eb1.z=__expf(xb1.z); eb1.w=__expf(xb1.w);
    ((f32x4*)rows[w][0])[lane]      = ea0;
    ((f32x4*)rows[w][0])[lane + 64] = ea1;
    ((f32x4*)rows[w][1])[lane]      = eb0;
    ((f32x4*)rows[w][1])[lane + 64] = eb1;
    float sa = ea0.x+ea0.y+ea0.z+ea0.w + ea1.x+ea1.y+ea1.z+ea1.w;
    float sb = eb0.x+eb0.y+eb0.z+eb0.w + eb1.x+eb1.y+eb1.z+eb1.w;
#pragma unroll
    for (int o = 32; o; o >>= 1) { sa += __shfl_xor(sa, o, 64); sb += __shfl_xor(sb, o, 64); }

#pragma unroll
    for (int rr = 0; rr < 2; ++rr) {
        const int r = rbase + rr;
        const int b = r & (B - 1), t = r >> 6;    // r = t*B + b
        const float* rw = rows[w][rr];
        const int lab_len = label_lens[b];
        const int off     = offsets[b];
        const float ubk   = rw[0];
        const int j0 = 4 * lane;
        float q0 = (j0 + 0 < lab_len) ? rw[labels[min(off + j0 + 0, B * L - 1)]] : ubk;
        float q1 = (j0 + 1 < lab_len) ? rw[labels[min(off + j0 + 1, B * L - 1)]] : ubk;
        float q2 = (j0 + 2 < lab_len) ? rw[labels[min(off + j0 + 2, B * L - 1)]] : ubk;
        float q3 = (j0 + 3 < lab_len) ? rw[labels[min(off + j0 + 3, B * L - 1)]] : ubk;
        ushort4 hv = {f2bf(q0), f2bf(q1), f2bf(q2), f2bf(q3)};
        ((ushort4*)packedU)[(size_t)(b * T + t) * 64 + lane] = hv;
        if (lane == 0) {
            lse_rows[b * T + t] = __logf(rr ? sb : sa);
            blankU[b * T + t]   = ubk;
        }
    }
}

// ---------------------------------------------------------------------------
// Fwd/bwd linear-space CTC scan, REGISTER-resident chunks. The R4-R6/LDS-era
// structure exposed ~2 LDS latencies per step (380 cyc/step) because every
// step's ds_read_b64 + ds_read_b32 sat on the in-order lgkm queue with the
// shfl bpermutes. Per-lane chunk data is only 128 B -> hold the current and
// next chunk in uint2[16] register buffers filled by bulk coalesced
// global_load_dwordx2 (issued one full chunk ahead; vmcnt covered by the
// previous chunk's ~700 cyc of compute). Blank row values ride one coalesced
// load + v_readlane broadcast. The ONLY lgkm op per step is the single
// boundary shuffle. Backward scan remapped to states 8l+1..8l+8 per lane
// (state 0 in A8@lane0) so it needs ONE shuffle per step instead of two.
// Rescale cadence 16 (chunk growth <= e^~64 << e^88 fp32 ceiling).
// ---------------------------------------------------------------------------
__global__ __launch_bounds__(128, 1) void ctc_kernel(
    const int* __restrict__ labels, const int* __restrict__ act_lens,
    const int* __restrict__ label_lens, const int* __restrict__ offsets,
    const float* __restrict__ lse_rows, const unsigned short* __restrict__ packedU,
    const float* __restrict__ blankU, float* __restrict__ out)
{
    __shared__ float sbr[S];
    __shared__ float s_accb;

    const int b    = blockIdx.x;
    const int wave = threadIdx.x >> 6;
    const int lane = threadIdx.x & 63;
    const int lab_len = label_lens[b];
    const int a_len   = act_lens[b];
    const int th      = (a_len - 1) >> 1;
    const int off     = offsets[b];
    const size_t rowbase = (size_t)b * T;

    int li0 = 4 * lane;
    int eprev = (li0 - 1 >= 0 && li0 - 1 < lab_len) ? labels[min(off + li0 - 1, B * L - 1)] : 0;
    int enext = (li0 + 4 < lab_len) ? labels[min(off + li0 + 4, B * L - 1)] : 0;
    int e0 = (li0 + 0 < lab_len) ? labels[min(off + li0 + 0, B * L - 1)] : 0;
    int e1 = (li0 + 1 < lab_len) ? labels[min(off + li0 + 1, B * L - 1)] : 0;
    int e2 = (li0 + 2 < lab_len) ? labels[min(off + li0 + 2, B * L - 1)] : 0;
    int e3 = (li0 + 3 < lab_len) ? labels[min(off + li0 + 3, B * L - 1)] : 0;

    // skip-allow flags for odd states 8l+1,3,5,7 (same for fwd & bwd mappings)
    const float aF0 = (8 * lane + 1 >= 2 && e0 != 0 && e0 != eprev) ? 1.f : 0.f;
    const float aF1 = (e1 != 0 && e1 != e0) ? 1.f : 0.f;
    const float aF2 = (e2 != 0 && e2 != e1) ? 1.f : 0.f;
    const float aF3 = (e3 != 0 && e3 != e2) ? 1.f : 0.f;
    const float aB0 = aF1, aB1 = aF2, aB2 = aF3;
    const float aB3 = (enext != 0 && enext != e3) ? 1.f : 0.f;

    float A0 = 0.f, A1 = 0.f, A2 = 0.f, A3 = 0.f, A4 = 0.f,
          A5 = 0.f, A6 = 0.f, A7 = 0.f, A8 = 0.f;
    float acc = 0.f, sls = 0.f;

    uint2 Ua[C], Ub[C];         // static-indexed -> registers
    float Ka = 0.f, Kb = 0.f;   // blank rows: lane (i&15) holds row i

#define LOADCH(U, K, TLO) do {                                                \
        const int tl_ = min(max((int)(TLO), 0), T - C);                       \
        const uint2* gp_ = (const uint2*)(packedU + (rowbase + tl_) * 256);   \
        _Pragma("unroll")                                                     \
        for (int i_ = 0; i_ < C; ++i_) U[i_] = gp_[i_ * 64 + lane];           \
        K = blankU[rowbase + tl_ + (lane & (C - 1))];                         \
    } while (0)

#define RESCALE() do {                                                        \
        float m_ = fmaxf(A8, A0); m_ = fmaxf(m_, A1); m_ = fmaxf(m_, A2);     \
        m_ = fmaxf(m_, A3); m_ = fmaxf(m_, A4); m_ = fmaxf(m_, A5);           \
        m_ = fmaxf(m_, A6); m_ = fmaxf(m_, A7);                               \
        _Pragma("unroll")                                                     \
        for (int o_ = 32; o_; o_ >>= 1) m_ = fmaxf(m_, __shfl_xor(m_, o_, 64)); \
        m_ = fmaxf(m_, 1e-30f);                                               \
        float inv_ = __builtin_amdgcn_rcpf(m_);                               \
        acc += __logf(m_);                                                    \
        A0 *= inv_; A1 *= inv_; A2 *= inv_; A3 *= inv_; A4 *= inv_;           \
        A5 *= inv_; A6 *= inv_; A7 *= inv_; A8 *= inv_;                       \
    } while (0)

    // fwd: lane holds states 8l..8l+7 (A0..A7), A8 = state 512 on lane 63
#define STEPF_CORE(HX, HY, UB) do {                                           \
        const float ub_ = (UB);                                               \
        const unsigned hx_ = (HX), hy_ = (HY);                                \
        const float u0_ = __uint_as_float(hx_ << 16);                         \
        const float u1_ = __uint_as_float(hx_ & 0xffff0000u);                 \
        const float u2_ = __uint_as_float(hy_ << 16);                         \
        const float u3_ = __uint_as_float(hy_ & 0xffff0000u);                 \
        float pA7_ = __shfl_up(A7, 1, 64);                                    \
        if (lane == 0) pA7_ = 0.f;                                            \
        A8 = ub_ * (A8 + A7);                                                 \
        A7 = u3_ * fmaf(aF3, A5, A7 + A6);                                    \
        A6 = ub_ * (A6 + A5);                                                 \
        A5 = u2_ * fmaf(aF2, A3, A5 + A4);                                    \
        A4 = ub_ * (A4 + A3);                                                 \
        A3 = u1_ * fmaf(aF1, A1, A3 + A2);                                    \
        A2 = ub_ * (A2 + A1);                                                 \
        A1 = u0_ * fmaf(aF0, pA7_, A1 + A0);                                  \
        A0 = ub_ * (A0 + pA7_);                                               \
    } while (0)
#define STEPF_R(U, K, I) STEPF_CORE(U[I].x, U[I].y, lane_bcast(K, I))

    // bwd: lane holds states 8l+1..8l+8 (A0..A7), A8 = state 0 on lane 0.
    // Needs only the neighbor's lowest state (s=8l+9) -> ONE shfl_down.
#define STEPB_CORE(HX, HY, UB) do {                                           \
        const float ub_ = (UB);                                               \
        const unsigned hx_ = (HX), hy_ = (HY);                                \
        const float u0_ = __uint_as_float(hx_ << 16);                         \
        const float u1_ = __uint_as_float(hx_ & 0xffff0000u);                 \
        const float u2_ = __uint_as_float(hy_ << 16);                         \
        const float u3_ = __uint_as_float(hy_ & 0xffff0000u);                 \
        float nC0_ = __shfl_down(A0, 1, 64);                                  \
        if (lane == 63) nC0_ = 0.f;                                           \
        A8 = ub_ * (A8 + A0);                                                 \
        A0 = u0_ * fmaf(aB0, A2, A0 + A1);                                    \
        A1 = ub_ * (A1 + A2);                                                 \
        A2 = u1_ * fmaf(aB1, A4, A2 + A3);                                    \
        A3 = ub_ * (A3 + A4);                                                 \
        A4 = u2_ * fmaf(aB2, A6, A4 + A5);                                    \
        A5 = ub_ * (A5 + A6);                                                 \
        A6 = u3_ * fmaf(aB3, nC0_, A6 + A7);                                  \
        A7 = ub_ * (A7 + nC0_);                                               \
    } while (0)
#define STEPB_R(U, K, I) STEPB_CORE(U[I].x, U[I].y, lane_bcast(K, I))

#define STEP_DIRECT(WHICH, TT) do {                                           \
        uint2 hvd_ = ((const uint2*)(packedU + (rowbase + (TT)) * 256))[lane];\
        float ubd_ = blankU[rowbase + (TT)];                                  \
        WHICH(hvd_.x, hvd_.y, ubd_);                                          \
    } while (0)

    if (wave == 0) {
        for (int t = lane; t < a_len; t += 64) sls += lse_rows[rowbase + t];
#pragma unroll
        for (int o = 32; o; o >>= 1) sls += __shfl_xor(sls, o, 64);

        if (lane == 0) {
            A0 = blankU[rowbase];
            A1 = __uint_as_float(((unsigned)packedU[rowbase * 256]) << 16);
        }

        if (th >= 1) {
            const int kfull = (th - 15) >> 4;       // chunks 1..kfull fully valid
            LOADCH(Ua, Ka, 0);
            LOADCH(Ub, Kb, 16);
            // chunk 0: steps t = 1..min(15, th)
#pragma unroll
            for (int i = 1; i < C; ++i) { if (i <= th) STEPF_R(Ua, Ka, i); }
            RESCALE();
            LOADCH(Ua, Ka, 32);
            int k = 1;
            for (; k + 1 <= kfull; k += 2) {
#pragma unroll
                for (int i = 0; i < C; ++i) STEPF_R(Ub, Kb, i);
                RESCALE();
                LOADCH(Ub, Kb, 16 * (k + 2));
#pragma unroll
                for (int i = 0; i < C; ++i) STEPF_R(Ua, Ka, i);
                RESCALE();
                LOADCH(Ua, Ka, 16 * (k + 3));
            }
            if (k <= kfull) {                       // leftover full chunk (in Ub)
#pragma unroll
                for (int i = 0; i < C; ++i) STEPF_R(Ub, Kb, i);
                RESCALE();
            }
            // ragged tail (none for a_len=1024): direct per-step loads
            const int tS = (kfull >= 1) ? 16 * (kfull + 1) : 16;
            for (int t = tS; t <= th; ++t) {
                STEP_DIRECT(STEPF_CORE, t);
                if (((t - tS) & 7) == 7) RESCALE();
            }
        }
    } else {
        const int send = 2 * lab_len;
        {
            size_t rl = rowbase + (a_len - 1);
            float ubl = blankU[rl];
            float ue  = (lab_len > 0)
                      ? __uint_as_float(((unsigned)packedU[rl * 256 + (lab_len - 1)]) << 16)
                      : 0.f;
            int s0 = 8 * lane + 1;                  // states s0..s0+7
            A0 = (s0 + 0 == send) ? ubl : ((s0 + 0 == send - 1) ? ue : 0.f);
            A1 = (s0 + 1 == send) ? ubl : ((s0 + 1 == send - 1) ? ue : 0.f);
            A2 = (s0 + 2 == send) ? ubl : ((s0 + 2 == send - 1) ? ue : 0.f);
            A3 = (s0 + 3 == send) ? ubl : ((s0 + 3 == send - 1) ? ue : 0.f);
            A4 = (s0 + 4 == send) ? ubl : ((s0 + 4 == send - 1) ? ue : 0.f);
            A5 = (s0 + 5 == send) ? ubl : ((s0 + 5 == send - 1) ? ue : 0.f);
            A6 = (s0 + 6 == send) ? ubl : ((s0 + 6 == send - 1) ? ue : 0.f);
            A7 = (s0 + 7 == send) ? ubl : ((s0 + 7 == send - 1) ? ue : 0.f);
            A8 = (send == 0) ? ubl : 0.f;           // state 0 (lane 0's only used)
        }

        const int nstB = a_len - 2 - th;            // steps t = a_len-2 .. th+1
        if (nstB > 0 && a_len >= 16) {
            const int cfull = (a_len - th - 17) >> 4;   // chunks 1..cfull full
            LOADCH(Ua, Ka, a_len - 16);
            LOADCH(Ub, Kb, a_len - 32);
            // chunk 0 rows [a_len-16, a_len-1]; i=15 (t=a_len-1) never a step
#pragma unroll
            for (int i = C - 2; i >= 0; --i) {
                if (a_len - 16 + i >= th + 1) STEPB_R(Ua, Ka, i);
            }
            RESCALE();
            LOADCH(Ua, Ka, a_len - 48);
            int c = 1;
            for (; c + 1 <= cfull; c += 2) {
#pragma unroll
                for (int i = C - 1; i >= 0; --i) STEPB_R(Ub, Kb, i);
                RESCALE();
                LOADCH(Ub, Kb, a_len - 16 * (c + 3));
#pragma unroll
                for (int i = C - 1; i >= 0; --i) STEPB_R(Ua, Ka, i);
                RESCALE();
                LOADCH(Ua, Ka, a_len - 16 * (c + 4));
            }
            if (c <= cfull) {                       // leftover full chunk (in Ub)
#pragma unroll
                for (int i = C - 1; i >= 0; --i) STEPB_R(Ub, Kb, i);
                RESCALE();
            }
            const int cf = (cfull >= 1) ? cfull : 0;
            const int tE = a_len - 16 * (cf + 1) - 1;   // ragged tail (none @1024)
            for (int t = tE; t >= th + 1; --t) {
                STEP_DIRECT(STEPB_CORE, t);
                if (((tE - t) & 7) == 7) RESCALE();
            }
        } else if (nstB > 0) {                      // tiny a_len fallback
            for (int t = a_len - 2; t >= th + 1; --t) {
                STEP_DIRECT(STEPB_CORE, t);
                if (((a_len - 2 - t) & 7) == 7) RESCALE();
            }
        }

        {   // bracket W(s) = B(s) + B(s+1) + allow(s+2)*B(s+2), B = beta_{th+1}
            float nC0 = __shfl_down(A0, 1, 64);
            if (lane == 63) nC0 = 0.f;
            float w1 = fmaf(aB0, A2, A0 + A1);      // s = 8l+1
            float w2 = A1 + A2;                     // s = 8l+2
            float w3 = fmaf(aB1, A4, A2 + A3);      // s = 8l+3
            float w4 = A3 + A4;                     // s = 8l+4
            float w5 = fmaf(aB2, A6, A4 + A5);      // s = 8l+5
            float w6 = A5 + A6;                     // s = 8l+6
            float w7 = fmaf(aB3, nC0, A6 + A7);     // s = 8l+7
            float w8 = A7 + nC0;                    // s = 8l+8
            int sB = 8 * lane + 1;
            sbr[sB + 0] = w1; sbr[sB + 1] = w2; sbr[sB + 2] = w3; sbr[sB + 3] = w4;
            sbr[sB + 4] = w5; sbr[sB + 5] = w6; sbr[sB + 6] = w7; sbr[sB + 7] = w8;
            if (lane == 0) sbr[0] = A8 + A0;        // W(0) = B(0) + B(1)
            if (lane == 0) s_accb = acc;
        }
    }
    __syncthreads();
    if (wave == 0) {
        // LOG-space junction (linear dot of the two independently-rescaled
        // sides underflows fp32)
        int s0 = 8 * lane;
        float p0 = __logf(fmaxf(A0, 1e-37f)) + __logf(fmaxf(sbr[s0 + 0], 1e-37f));
        float p1 = __logf(fmaxf(A1, 1e-37f)) + __logf(fmaxf(sbr[s0 + 1], 1e-37f));
        float p2 = __logf(fmaxf(A2, 1e-37f)) + __logf(fmaxf(sbr[s0 + 2], 1e-37f));
        float p3 = __logf(fmaxf(A3, 1e-37f)) + __logf(fmaxf(sbr[s0 + 3], 1e-37f));
        float p4 = __logf(fmaxf(A4, 1e-37f)) + __logf(fmaxf(sbr[s0 + 4], 1e-37f));
        float p5 = __logf(fmaxf(A5, 1e-37f)) + __logf(fmaxf(sbr[s0 + 5], 1e-37f));
        float p6 = __logf(fmaxf(A6, 1e-37f)) + __logf(fmaxf(sbr[s0 + 6], 1e-37f));
        float p7 = __logf(fmaxf(A7, 1e-37f)) + __logf(fmaxf(sbr[s0 + 7], 1e-37f));
        float p8 = -3.0e38f;
        if (lane == 63) p8 = __logf(fmaxf(A8, 1e-37f)) + __logf(fmaxf(sbr[512], 1e-37f));
        float pmax = fmaxf(fmaxf(fmaxf(p0, p1), fmaxf(p2, p3)),
                           fmaxf(fmaxf(p4, p5), fmaxf(p6, p7)));
        pmax = fmaxf(pmax, p8);
#pragma unroll
        for (int o = 32; o; o >>= 1) pmax = fmaxf(pmax, __shfl_xor(pmax, o, 64));
        float dot = __expf(p0 - pmax) + __expf(p1 - pmax) + __expf(p2 - pmax)
                  + __expf(p3 - pmax) + __expf(p4 - pmax) + __expf(p5 - pmax)
                  + __expf(p6 - pmax) + __expf(p7 - pmax);
        if (lane == 63) dot += __expf(p8 - pmax);
#pragma unroll
        for (int o = 32; o; o >>= 1) dot += __shfl_xor(dot, o, 64);
        if (lane == 0) {
            float loss = sls - acc - s_accb - (pmax + __logf(dot));
            atomicAdd(out, loss);
        }
    }
#undef LOADCH
#undef RESCALE
#undef STEPF_CORE
#undef STEPF_R
#undef STEPB_CORE
#undef STEPB_R
#undef STEP_DIRECT
}

extern "C" void kernel_launch(void* const* d_in, const int* in_sizes, int n_in,
                              void* d_out, int out_size, void* d_ws, size_t ws_size,
                              hipStream_t stream) {
    const float* acts       = (const float*)d_in[0];
    const int*   labels     = (const int*)d_in[1];
    const int*   act_lens   = (const int*)d_in[2];
    const int*   label_lens = (const int*)d_in[3];
    float*       out        = (float*)d_out;

    float*          lse_rows = (float*)d_ws;
    float*          blankU   = (float*)((char*)d_ws + (size_t)T * B * 4);
    int*            offsets  = (int*)  ((char*)d_ws + (size_t)2 * T * B * 4);
    unsigned short* packedU  = (unsigned short*)((char*)d_ws + (1u << 20));

    hipMemsetAsync(d_out, 0, sizeof(float), stream);

    offsets_kernel<<<1, 64, 0, stream>>>(label_lens, offsets);
    setup_kernel<<<T * B / 8, 256, 0, stream>>>(
        acts, labels, label_lens, offsets, lse_rows, packedU, blankU);
    ctc_kernel<<<B, 128, 0, stream>>>(
        labels, act_lens, label_lens, offsets, lse_rows, packedU, blankU, out);
}

// Round 3
// 246.298 us; speedup vs baseline: 1.1342x; 1.0165x over previous
//
#include <hip/hip_runtime.h>

constexpr int T = 1024;
constexpr int B = 64;
constexpr int V = 512;
constexpr int L = 256;
constexpr int S = 2 * L + 1;   // 513
constexpr int C = 16;          // scan chunk rows (128 B/lane, register-resident)

typedef float f32x4 __attribute__((ext_vector_type(4)));

__device__ __forceinline__ unsigned short f2bf(float f) {  // RNE
    unsigned u = __float_as_uint(f);
    u += 0x7fffu + ((u >> 16) & 1u);
    return (unsigned short)(u >> 16);
}

__device__ __forceinline__ float lane_bcast(float v, int i) {
    return __uint_as_float((unsigned)__builtin_amdgcn_readlane((int)__float_as_uint(v), i));
}

// DPP lane shifts: pure VALU (no lgkm). Direction per LLVM AtomicOptimizer:
// WAVE_SHR1 (0x138): lane n <- lane n-1 (== __shfl_up by 1), lane 0 -> 0.
// WAVE_SHL1 (0x130): lane n <- lane n+1 (== __shfl_down by 1), lane 63 -> 0.
__device__ __forceinline__ float dpp_shr1z(float x) {
    return __uint_as_float((unsigned)__builtin_amdgcn_update_dpp(
        0, (int)__float_as_uint(x), 0x138, 0xf, 0xf, true));
}
__device__ __forceinline__ float dpp_shl1z(float x) {
    return __uint_as_float((unsigned)__builtin_amdgcn_update_dpp(
        0, (int)__float_as_uint(x), 0x130, 0xf, 0xf, true));
}
// one level of a DPP max-reduce ladder (invalid/masked lanes keep old = identity)
template <int CTRL, int RM>
__device__ __forceinline__ float dppmax(float m) {
    int mi = (int)__float_as_uint(m);
    int t = __builtin_amdgcn_update_dpp(mi, mi, CTRL, RM, 0xf, false);
    return fmaxf(m, __uint_as_float((unsigned)t));
}

// ws layout (batch-major):
// [0]      lse_rows : B*T floats (256 KB)   [b*T+t]
// [256K]   blankU   : B*T floats (256 KB)   [b*T+t]  exp(blank logit)
// [512K]   offsets  : B ints
// [1M]     packedU  : B*T*256 bf16 (32 MB)  [(b*T+t)*256+j] exp(label logits)

__global__ __launch_bounds__(64) void offsets_kernel(
    const int* __restrict__ label_lens, int* __restrict__ offsets)
{
    int lane = threadIdx.x;
    int v = (lane < B) ? label_lens[lane] : 0;
    int x = v;
#pragma unroll
    for (int o = 1; o < 64; o <<= 1) {
        int y = __shfl_up(x, o, 64);
        if (lane >= o) x += y;
    }
    if (lane < B) offsets[lane] = x - v;
}

// ---------------------------------------------------------------------------
// Setup: one wave per TWO (t,b) rows. exp the rows once; emit row-lse + bf16
// exp(label logits) + blank, all in BATCH-MAJOR layout.
// ---------------------------------------------------------------------------
__global__ __launch_bounds__(256) void setup_kernel(
    const float* __restrict__ acts, const int* __restrict__ labels,
    const int* __restrict__ label_lens, const int* __restrict__ offsets,
    float* __restrict__ lse_rows, unsigned short* __restrict__ packedU,
    float* __restrict__ blankU)
{
    __shared__ float rows[4][2][V];          // 16 KB
    const int w    = threadIdx.x >> 6;
    const int lane = threadIdx.x & 63;
    const int rbase = (blockIdx.x * 4 + w) * 2;     // rows rbase, rbase+1
    const f32x4* p = (const f32x4*)(acts + (size_t)rbase * V);

    f32x4 xa0 = __builtin_nontemporal_load(p + lane);
    f32x4 xa1 = __builtin_nontemporal_load(p + lane + 64);
    f32x4 xb0 = __builtin_nontemporal_load(p + lane + 128);
    f32x4 xb1 = __builtin_nontemporal_load(p + lane + 192);
    f32x4 ea0, ea1, eb0, eb1;
    ea0.x=__expf(xa0.x); ea0.y=__expf(xa0.y); ea0.z=__expf(xa0.z); ea0.w=__expf(xa0.w);
    ea1.x=__expf(xa1.x); ea1.y=__expf(xa1.y); ea1.z=__expf(xa1.z); ea1.w=__expf(xa1.w);
    eb0.x=__expf(xb0.x); eb0.y=__expf(xb0.y); eb0.z=__expf(xb0.z); eb0.w=__expf(xb0.w);
    eb1.x=__expf(xb1.x); eb1.y=__expf(xb1.y); eb1.z=__expf(xb1.z); eb1.w=__expf(xb1.w);
    ((f32x4*)rows[w][0])[lane]      = ea0;
    ((f32x4*)rows[w][0])[lane + 64] = ea1;
    ((f32x4*)rows[w][1])[lane]      = eb0;
    ((f32x4*)rows[w][1])[lane + 64] = eb1;
    float sa = ea0.x+ea0.y+ea0.z+ea0.w + ea1.x+ea1.y+ea1.z+ea1.w;
    float sb = eb0.x+eb0.y+eb0.z+eb0.w + eb1.x+eb1.y+eb1.z+eb1.w;
#pragma unroll
    for (int o = 32; o; o >>= 1) { sa += __shfl_xor(sa, o, 64); sb += __shfl_xor(sb, o, 64); }

#pragma unroll
    for (int rr = 0; rr < 2; ++rr) {
        const int r = rbase + rr;
        const int b = r & (B - 1), t = r >> 6;    // r = t*B + b
        const float* rw = rows[w][rr];
        const int lab_len = label_lens[b];
        const int off     = offsets[b];
        const float ubk   = rw[0];
        const int j0 = 4 * lane;
        float q0 = (j0 + 0 < lab_len) ? rw[labels[min(off + j0 + 0, B * L - 1)]] : ubk;
        float q1 = (j0 + 1 < lab_len) ? rw[labels[min(off + j0 + 1, B * L - 1)]] : ubk;
        float q2 = (j0 + 2 < lab_len) ? rw[labels[min(off + j0 + 2, B * L - 1)]] : ubk;
        float q3 = (j0 + 3 < lab_len) ? rw[labels[min(off + j0 + 3, B * L - 1)]] : ubk;
        ushort4 hv = {f2bf(q0), f2bf(q1), f2bf(q2), f2bf(q3)};
        ((ushort4*)packedU)[(size_t)(b * T + t) * 64 + lane] = hv;
        if (lane == 0) {
            lse_rows[b * T + t] = __logf(rr ? sb : sa);
            blankU[b * T + t]   = ubk;
        }
    }
}

// ---------------------------------------------------------------------------
// Fwd/bwd linear-space CTC scan. R7 made chunks register-resident (bulk
// coalesced global loads, no LDS staging). R8: the serial loop is now 100%
// VALU — the per-step __shfl (ds_bpermute, ~60cyc lgkm with zero TLP) is a
// 1-inst DPP wave shift, and RESCALE's 6-level __shfl_xor reduce (~400cyc)
// is a DPP row_shr/bcast ladder + readlane. No lgkm ops anywhere in the
// steady state; one vmcnt wait per chunk, covered by TRIPLE-buffered
// prefetch issued 2 chunks (~1800 cyc) ahead of use.
// ---------------------------------------------------------------------------
__global__ __launch_bounds__(128, 1) void ctc_kernel(
    const int* __restrict__ labels, const int* __restrict__ act_lens,
    const int* __restrict__ label_lens, const int* __restrict__ offsets,
    const float* __restrict__ lse_rows, const unsigned short* __restrict__ packedU,
    const float* __restrict__ blankU, float* __restrict__ out)
{
    __shared__ float sbr[S];
    __shared__ float s_accb;

    const int b    = blockIdx.x;
    const int wave = threadIdx.x >> 6;
    const int lane = threadIdx.x & 63;
    const int lab_len = label_lens[b];
    const int a_len   = act_lens[b];
    const int th      = (a_len - 1) >> 1;
    const int thp1    = th + 1;
    const int off     = offsets[b];
    const size_t rowbase = (size_t)b * T;

    int li0 = 4 * lane;
    int eprev = (li0 - 1 >= 0 && li0 - 1 < lab_len) ? labels[min(off + li0 - 1, B * L - 1)] : 0;
    int enext = (li0 + 4 < lab_len) ? labels[min(off + li0 + 4, B * L - 1)] : 0;
    int e0 = (li0 + 0 < lab_len) ? labels[min(off + li0 + 0, B * L - 1)] : 0;
    int e1 = (li0 + 1 < lab_len) ? labels[min(off + li0 + 1, B * L - 1)] : 0;
    int e2 = (li0 + 2 < lab_len) ? labels[min(off + li0 + 2, B * L - 1)] : 0;
    int e3 = (li0 + 3 < lab_len) ? labels[min(off + li0 + 3, B * L - 1)] : 0;

    // skip-allow flags for odd states 8l+1,3,5,7 (same for fwd & bwd mappings)
    const float aF0 = (8 * lane + 1 >= 2 && e0 != 0 && e0 != eprev) ? 1.f : 0.f;
    const float aF1 = (e1 != 0 && e1 != e0) ? 1.f : 0.f;
    const float aF2 = (e2 != 0 && e2 != e1) ? 1.f : 0.f;
    const float aF3 = (e3 != 0 && e3 != e2) ? 1.f : 0.f;
    const float aB0 = aF1, aB1 = aF2, aB2 = aF3;
    const float aB3 = (enext != 0 && enext != e3) ? 1.f : 0.f;

    float A0 = 0.f, A1 = 0.f, A2 = 0.f, A3 = 0.f, A4 = 0.f,
          A5 = 0.f, A6 = 0.f, A7 = 0.f, A8 = 0.f;
    float acc = 0.f, sls = 0.f;

    uint2 U0[C], U1[C], U2[C];      // static-indexed -> registers
    float K0 = 0.f, K1 = 0.f, K2 = 0.f;  // blank rows: lane (i&15) holds row i

#define LOADCH(U, K, TLO) do {                                                \
        const int tl_ = min(max((int)(TLO), 0), T - C);                       \
        const uint2* gp_ = (const uint2*)(packedU + (rowbase + tl_) * 256);   \
        _Pragma("unroll")                                                     \
        for (int i_ = 0; i_ < C; ++i_) U[i_] = gp_[i_ * 64 + lane];           \
        K = blankU[rowbase + tl_ + (lane & (C - 1))];                         \
    } while (0)

#define RESCALE() do {                                                        \
        float m_ = fmaxf(A8, A0); m_ = fmaxf(m_, A1); m_ = fmaxf(m_, A2);     \
        m_ = fmaxf(m_, A3); m_ = fmaxf(m_, A4); m_ = fmaxf(m_, A5);           \
        m_ = fmaxf(m_, A6); m_ = fmaxf(m_, A7);                               \
        m_ = dppmax<0x111, 0xf>(m_);  /* row_shr:1 */                         \
        m_ = dppmax<0x112, 0xf>(m_);  /* row_shr:2 */                         \
        m_ = dppmax<0x114, 0xf>(m_);  /* row_shr:4 */                         \
        m_ = dppmax<0x118, 0xf>(m_);  /* row_shr:8 */                         \
        m_ = dppmax<0x142, 0xa>(m_);  /* bcast15 -> rows 1,3 */               \
        m_ = dppmax<0x143, 0xc>(m_);  /* bcast31 -> rows 2,3 */               \
        m_ = lane_bcast(m_, 63);                                              \
        m_ = fmaxf(m_, 1e-30f);                                               \
        float inv_ = __builtin_amdgcn_rcpf(m_);                               \
        acc += __logf(m_);                                                    \
        A0 *= inv_; A1 *= inv_; A2 *= inv_; A3 *= inv_; A4 *= inv_;           \
        A5 *= inv_; A6 *= inv_; A7 *= inv_; A8 *= inv_;                       \
    } while (0)

    // fwd: lane holds states 8l..8l+7 (A0..A7), A8 = state 512 on lane 63
#define STEPF_CORE(HX, HY, UB) do {                                           \
        const float ub_ = (UB);                                               \
        const unsigned hx_ = (HX), hy_ = (HY);                                \
        const float u0_ = __uint_as_float(hx_ << 16);                         \
        const float u1_ = __uint_as_float(hx_ & 0xffff0000u);                 \
        const float u2_ = __uint_as_float(hy_ << 16);                         \
        const float u3_ = __uint_as_float(hy_ & 0xffff0000u);                 \
        const float pA7_ = dpp_shr1z(A7);                                     \
        A8 = ub_ * (A8 + A7);                                                 \
        A7 = u3_ * fmaf(aF3, A5, A7 + A6);                                    \
        A6 = ub_ * (A6 + A5);                                                 \
        A5 = u2_ * fmaf(aF2, A3, A5 + A4);                                    \
        A4 = ub_ * (A4 + A3);                                                 \
        A3 = u1_ * fmaf(aF1, A1, A3 + A2);                                    \
        A2 = ub_ * (A2 + A1);                                                 \
        A1 = u0_ * fmaf(aF0, pA7_, A1 + A0);                                  \
        A0 = ub_ * (A0 + pA7_);                                               \
    } while (0)
#define STEPF_R(U, K, I) STEPF_CORE(U[I].x, U[I].y, lane_bcast(K, I))

    // bwd: lane holds states 8l+1..8l+8 (A0..A7), A8 = state 0 on lane 0.
    // Needs only the neighbor's lowest state (s=8l+9) -> ONE dpp shift.
#define STEPB_CORE(HX, HY, UB) do {                                           \
        const float ub_ = (UB);                                               \
        const unsigned hx_ = (HX), hy_ = (HY);                                \
        const float u0_ = __uint_as_float(hx_ << 16);                         \
        const float u1_ = __uint_as_float(hx_ & 0xffff0000u);                 \
        const float u2_ = __uint_as_float(hy_ << 16);                         \
        const float u3_ = __uint_as_float(hy_ & 0xffff0000u);                 \
        const float nC0_ = dpp_shl1z(A0);                                     \
        A8 = ub_ * (A8 + A0);                                                 \
        A0 = u0_ * fmaf(aB0, A2, A0 + A1);                                    \
        A1 = ub_ * (A1 + A2);                                                 \
        A2 = u1_ * fmaf(aB1, A4, A2 + A3);                                    \
        A3 = ub_ * (A3 + A4);                                                 \
        A4 = u2_ * fmaf(aB2, A6, A4 + A5);                                    \
        A5 = ub_ * (A5 + A6);                                                 \
        A6 = u3_ * fmaf(aB3, nC0_, A6 + A7);                                  \
        A7 = ub_ * (A7 + nC0_);                                               \
    } while (0)
#define STEPB_R(U, K, I) STEPB_CORE(U[I].x, U[I].y, lane_bcast(K, I))

#define STEP_DIRECT(WHICH, TT) do {                                           \
        uint2 hvd_ = ((const uint2*)(packedU + (rowbase + (TT)) * 256))[lane];\
        float ubd_ = blankU[rowbase + (TT)];                                  \
        WHICH(hvd_.x, hvd_.y, ubd_);                                          \
    } while (0)

#define DOF16(U, K) do {                                                      \
        _Pragma("unroll")                                                     \
        for (int i_ = 0; i_ < C; ++i_) {                                      \
            STEPF_R(U, K, i_);                                                \
            if (i_ == 7 || i_ == 15) RESCALE();                               \
        }                                                                     \
    } while (0)
#define DOFPART(U, K, TLO) do {                                               \
        _Pragma("unroll")                                                     \
        for (int i_ = 0; i_ < C; ++i_) {                                      \
            if ((TLO) + i_ <= th) STEPF_R(U, K, i_);                          \
            if (i_ == 7 || i_ == 15) RESCALE();                               \
        }                                                                     \
    } while (0)
#define DOB16(U, K) do {                                                      \
        _Pragma("unroll")                                                     \
        for (int i_ = C - 1; i_ >= 0; --i_) {                                 \
            STEPB_R(U, K, i_);                                                \
            if (i_ == 8 || i_ == 0) RESCALE();                                \
        }                                                                     \
    } while (0)
#define DOBPART(U, K, TLO) do {                                               \
        _Pragma("unroll")                                                     \
        for (int i_ = C - 1; i_ >= 0; --i_) {                                 \
            if ((TLO) + i_ >= thp1) STEPB_R(U, K, i_);                        \
            if (i_ == 8 || i_ == 0) RESCALE();                                \
        }                                                                     \
    } while (0)

    if (wave == 0) {
        if (lane == 0) {
            A0 = blankU[rowbase];
            A1 = __uint_as_float(((unsigned)packedU[rowbase * 256]) << 16);
        }

        if (th >= 1) {
            const int nst   = th;           // steps t = 1..th, chunk c: tlo=1+16c
            const int nc    = (nst + C - 1) / C;
            const int nfull = nst / C;
            LOADCH(U0, K0, 1);
            LOADCH(U1, K1, 1 + C);
            LOADCH(U2, K2, 1 + 2 * C);

            // lse sum overlaps the first chunk's load latency
            for (int t = lane; t < a_len; t += 64) sls += lse_rows[rowbase + t];
#pragma unroll
            for (int o = 32; o; o >>= 1) sls += __shfl_xor(sls, o, 64);

            int c = 0;
            for (; c + 3 <= nfull; c += 3) {
                DOF16(U0, K0); LOADCH(U0, K0, 1 + C * (c + 3));
                DOF16(U1, K1); LOADCH(U1, K1, 1 + C * (c + 4));
                DOF16(U2, K2); LOADCH(U2, K2, 1 + C * (c + 5));
            }
            const int rem = nfull - c;
            if (rem == 0) {
                if (nc > nfull) DOFPART(U0, K0, 1 + C * c);
            } else if (rem == 1) {
                DOF16(U0, K0);
                if (nc > nfull) DOFPART(U1, K1, 1 + C * (c + 1));
            } else {
                DOF16(U0, K0); DOF16(U1, K1);
                if (nc > nfull) DOFPART(U2, K2, 1 + C * (c + 2));
            }
        } else {
            for (int t = lane; t < a_len; t += 64) sls += lse_rows[rowbase + t];
#pragma unroll
            for (int o = 32; o; o >>= 1) sls += __shfl_xor(sls, o, 64);
        }
    } else {
        const int send = 2 * lab_len;
        {
            size_t rl = rowbase + (a_len - 1);
            float ubl = blankU[rl];
            float ue  = (lab_len > 0)
                      ? __uint_as_float(((unsigned)packedU[rl * 256 + (lab_len - 1)]) << 16)
                      : 0.f;
            int s0 = 8 * lane + 1;                  // states s0..s0+7
            A0 = (s0 + 0 == send) ? ubl : ((s0 + 0 == send - 1) ? ue : 0.f);
            A1 = (s0 + 1 == send) ? ubl : ((s0 + 1 == send - 1) ? ue : 0.f);
            A2 = (s0 + 2 == send) ? ubl : ((s0 + 2 == send - 1) ? ue : 0.f);
            A3 = (s0 + 3 == send) ? ubl : ((s0 + 3 == send - 1) ? ue : 0.f);
            A4 = (s0 + 4 == send) ? ubl : ((s0 + 4 == send - 1) ? ue : 0.f);
            A5 = (s0 + 5 == send) ? ubl : ((s0 + 5 == send - 1) ? ue : 0.f);
            A6 = (s0 + 6 == send) ? ubl : ((s0 + 6 == send - 1) ? ue : 0.f);
            A7 = (s0 + 7 == send) ? ubl : ((s0 + 7 == send - 1) ? ue : 0.f);
            A8 = (send == 0) ? ubl : 0.f;           // state 0 (lane 0's only used)
        }

        const int nstB = a_len - 2 - th;            // steps t = a_len-2 .. th+1
        if (nstB > 0 && a_len >= 17) {
            // chunk c: tlo = a_len-17-16c, rows tlo..tlo+15 = steps (desc)
            const int nc    = (nstB + C - 1) / C;
            const int nfull = nstB / C;
            LOADCH(U0, K0, a_len - 17);
            LOADCH(U1, K1, a_len - 17 - C);
            LOADCH(U2, K2, a_len - 17 - 2 * C);
            int c = 0;
            for (; c + 3 <= nfull; c += 3) {
                DOB16(U0, K0); LOADCH(U0, K0, a_len - 17 - C * (c + 3));
                DOB16(U1, K1); LOADCH(U1, K1, a_len - 17 - C * (c + 4));
                DOB16(U2, K2); LOADCH(U2, K2, a_len - 17 - C * (c + 5));
            }
            const int rem = nfull - c;
            if (rem == 0) {
                if (nc > nfull) DOBPART(U0, K0, a_len - 17 - C * c);
            } else if (rem == 1) {
                DOB16(U0, K0);
                if (nc > nfull) DOBPART(U1, K1, a_len - 17 - C * (c + 1));
            } else {
                DOB16(U0, K0); DOB16(U1, K1);
                if (nc > nfull) DOBPART(U2, K2, a_len - 17 - C * (c + 2));
            }
        } else if (nstB > 0) {                      // tiny a_len fallback
            for (int t = a_len - 2; t >= thp1; --t) {
                STEP_DIRECT(STEPB_CORE, t);
                if (((a_len - 2 - t) & 7) == 7) RESCALE();
            }
        }

        {   // bracket W(s) = B(s) + B(s+1) + allow(s+2)*B(s+2), B = beta_{th+1}
            float nC0 = dpp_shl1z(A0);
            float w1 = fmaf(aB0, A2, A0 + A1);      // s = 8l+1
            float w2 = A1 + A2;                     // s = 8l+2
            float w3 = fmaf(aB1, A4, A2 + A3);      // s = 8l+3
            float w4 = A3 + A4;                     // s = 8l+4
            float w5 = fmaf(aB2, A6, A4 + A5);      // s = 8l+5
            float w6 = A5 + A6;                     // s = 8l+6
            float w7 = fmaf(aB3, nC0, A6 + A7);     // s = 8l+7
            float w8 = A7 + nC0;                    // s = 8l+8
            int sB = 8 * lane + 1;
            sbr[sB + 0] = w1; sbr[sB + 1] = w2; sbr[sB + 2] = w3; sbr[sB + 3] = w4;
            sbr[sB + 4] = w5; sbr[sB + 5] = w6; sbr[sB + 6] = w7; sbr[sB + 7] = w8;
            if (lane == 0) sbr[0] = A8 + A0;        // W(0) = B(0) + B(1)
            if (lane == 0) s_accb = acc;
        }
    }
    __syncthreads();
    if (wave == 0) {
        // LOG-space junction (linear dot of the two independently-rescaled
        // sides underflows fp32)
        int s0 = 8 * lane;
        float p0 = __logf(fmaxf(A0, 1e-37f)) + __logf(fmaxf(sbr[s0 + 0], 1e-37f));
        float p1 = __logf(fmaxf(A1, 1e-37f)) + __logf(fmaxf(sbr[s0 + 1], 1e-37f));
        float p2 = __logf(fmaxf(A2, 1e-37f)) + __logf(fmaxf(sbr[s0 + 2], 1e-37f));
        float p3 = __logf(fmaxf(A3, 1e-37f)) + __logf(fmaxf(sbr[s0 + 3], 1e-37f));
        float p4 = __logf(fmaxf(A4, 1e-37f)) + __logf(fmaxf(sbr[s0 + 4], 1e-37f));
        float p5 = __logf(fmaxf(A5, 1e-37f)) + __logf(fmaxf(sbr[s0 + 5], 1e-37f));
        float p6 = __logf(fmaxf(A6, 1e-37f)) + __logf(fmaxf(sbr[s0 + 6], 1e-37f));
        float p7 = __logf(fmaxf(A7, 1e-37f)) + __logf(fmaxf(sbr[s0 + 7], 1e-37f));
        float p8 = -3.0e38f;
        if (lane == 63) p8 = __logf(fmaxf(A8, 1e-37f)) + __logf(fmaxf(sbr[512], 1e-37f));
        float pmax = fmaxf(fmaxf(fmaxf(p0, p1), fmaxf(p2, p3)),
                           fmaxf(fmaxf(p4, p5), fmaxf(p6, p7)));
        pmax = fmaxf(pmax, p8);
#pragma unroll
        for (int o = 32; o; o >>= 1) pmax = fmaxf(pmax, __shfl_xor(pmax, o, 64));
        float dot = __expf(p0 - pmax) + __expf(p1 - pmax) + __expf(p2 - pmax)
                  + __expf(p3 - pmax) + __expf(p4 - pmax) + __expf(p5 - pmax)
                  + __expf(p6 - pmax) + __expf(p7 - pmax);
        if (lane == 63) dot += __expf(p8 - pmax);
#pragma unroll
        for (int o = 32; o; o >>= 1) dot += __shfl_xor(dot, o, 64);
        if (lane == 0) {
            float loss = sls - acc - s_accb - (pmax + __logf(dot));
            atomicAdd(out, loss);
        }
    }
#undef LOADCH
#undef RESCALE
#undef STEPF_CORE
#undef STEPF_R
#undef STEPB_CORE
#undef STEPB_R
#undef STEP_DIRECT
#undef DOF16
#undef DOFPART
#undef DOB16
#undef DOBPART
}

extern "C" void kernel_launch(void* const* d_in, const int* in_sizes, int n_in,
                              void* d_out, int out_size, void* d_ws, size_t ws_size,
                              hipStream_t stream) {
    const float* acts       = (const float*)d_in[0];
    const int*   labels     = (const int*)d_in[1];
    const int*   act_lens   = (const int*)d_in[2];
    const int*   label_lens = (const int*)d_in[3];
    float*       out        = (float*)d_out;

    float*          lse_rows = (float*)d_ws;
    float*          blankU   = (float*)((char*)d_ws + (size_t)T * B * 4);
    int*            offsets  = (int*)  ((char*)d_ws + (size_t)2 * T * B * 4);
    unsigned short* packedU  = (unsigned short*)((char*)d_ws + (1u << 20));

    hipMemsetAsync(d_out, 0, sizeof(float), stream);

    offsets_kernel<<<1, 64, 0, stream>>>(label_lens, offsets);
    setup_kernel<<<T * B / 8, 256, 0, stream>>>(
        acts, labels, label_lens, offsets, lse_rows, packedU, blankU);
    ctc_kernel<<<B, 128, 0, stream>>>(
        labels, act_lens, label_lens, offsets, lse_rows, packedU, blankU, out);
}

// Round 4
// 246.205 us; speedup vs baseline: 1.1347x; 1.0004x over previous
//
#include <hip/hip_runtime.h>

constexpr int T = 1024;
constexpr int B = 64;
constexpr int V = 512;
constexpr int L = 256;
constexpr int S = 2 * L + 1;   // 513
constexpr int C = 16;          // scan chunk rows (128 B/lane, register-resident)

typedef float f32x4 __attribute__((ext_vector_type(4)));

__device__ __forceinline__ unsigned short f2bf(float f) {  // RNE
    unsigned u = __float_as_uint(f);
    u += 0x7fffu + ((u >> 16) & 1u);
    return (unsigned short)(u >> 16);
}

__device__ __forceinline__ float lane_bcast(float v, int i) {
    return __uint_as_float((unsigned)__builtin_amdgcn_readlane((int)__float_as_uint(v), i));
}

// DPP lane shifts: pure VALU (no lgkm). Direction per LLVM AtomicOptimizer:
// WAVE_SHR1 (0x138): lane n <- lane n-1 (== __shfl_up by 1), lane 0 -> 0.
// WAVE_SHL1 (0x130): lane n <- lane n+1 (== __shfl_down by 1), lane 63 -> 0.
__device__ __forceinline__ float dpp_shr1z(float x) {
    return __uint_as_float((unsigned)__builtin_amdgcn_update_dpp(
        0, (int)__float_as_uint(x), 0x138, 0xf, 0xf, true));
}
__device__ __forceinline__ float dpp_shl1z(float x) {
    return __uint_as_float((unsigned)__builtin_amdgcn_update_dpp(
        0, (int)__float_as_uint(x), 0x130, 0xf, 0xf, true));
}
// one level of a DPP max-reduce ladder (invalid/masked lanes keep old = identity)
template <int CTRL, int RM>
__device__ __forceinline__ float dppmax(float m) {
    int mi = (int)__float_as_uint(m);
    int t = __builtin_amdgcn_update_dpp(mi, mi, CTRL, RM, 0xf, false);
    return fmaxf(m, __uint_as_float((unsigned)t));
}

// ws layout (batch-major):
// [0]      lse_rows : B*T floats (256 KB)   [b*T+t]
// [256K]   blankU   : B*T floats (256 KB)   [b*T+t]  exp(blank logit)
// [512K]   offsets  : B ints
// [1M]     packedU  : B*T*256 bf16 (32 MB)  [(b*T+t)*256+j] exp(label logits)

__global__ __launch_bounds__(64) void offsets_kernel(
    const int* __restrict__ label_lens, int* __restrict__ offsets)
{
    int lane = threadIdx.x;
    int v = (lane < B) ? label_lens[lane] : 0;
    int x = v;
#pragma unroll
    for (int o = 1; o < 64; o <<= 1) {
        int y = __shfl_up(x, o, 64);
        if (lane >= o) x += y;
    }
    if (lane < B) offsets[lane] = x - v;
}

// ---------------------------------------------------------------------------
// Setup: one wave per TWO (t,b) rows. exp the rows once; emit row-lse + bf16
// exp(label logits) + blank, all in BATCH-MAJOR layout.
// ---------------------------------------------------------------------------
__global__ __launch_bounds__(256) void setup_kernel(
    const float* __restrict__ acts, const int* __restrict__ labels,
    const int* __restrict__ label_lens, const int* __restrict__ offsets,
    float* __restrict__ lse_rows, unsigned short* __restrict__ packedU,
    float* __restrict__ blankU)
{
    __shared__ float rows[4][2][V];          // 16 KB
    const int w    = threadIdx.x >> 6;
    const int lane = threadIdx.x & 63;
    const int rbase = (blockIdx.x * 4 + w) * 2;     // rows rbase, rbase+1
    const f32x4* p = (const f32x4*)(acts + (size_t)rbase * V);

    f32x4 xa0 = __builtin_nontemporal_load(p + lane);
    f32x4 xa1 = __builtin_nontemporal_load(p + lane + 64);
    f32x4 xb0 = __builtin_nontemporal_load(p + lane + 128);
    f32x4 xb1 = __builtin_nontemporal_load(p + lane + 192);
    f32x4 ea0, ea1, eb0, eb1;
    ea0.x=__expf(xa0.x); ea0.y=__expf(xa0.y); ea0.z=__expf(xa0.z); ea0.w=__expf(xa0.w);
    ea1.x=__expf(xa1.x); ea1.y=__expf(xa1.y); ea1.z=__expf(xa1.z); ea1.w=__expf(xa1.w);
    eb0.x=__expf(xb0.x); eb0.y=__expf(xb0.y); eb0.z=__expf(xb0.z); eb0.w=__expf(xb0.w);
    eb1.x=__expf(xb1.x); eb1.y=__expf(xb1.y); eb1.z=__expf(xb1.z); eb1.w=__expf(xb1.w);
    ((f32x4*)rows[w][0])[lane]      = ea0;
    ((f32x4*)rows[w][0])[lane + 64] = ea1;
    ((f32x4*)rows[w][1])[lane]      = eb0;
    ((f32x4*)rows[w][1])[lane + 64] = eb1;
    float sa = ea0.x+ea0.y+ea0.z+ea0.w + ea1.x+ea1.y+ea1.z+ea1.w;
    float sb = eb0.x+eb0.y+eb0.z+eb0.w + eb1.x+eb1.y+eb1.z+eb1.w;
#pragma unroll
    for (int o = 32; o; o >>= 1) { sa += __shfl_xor(sa, o, 64); sb += __shfl_xor(sb, o, 64); }

#pragma unroll
    for (int rr = 0; rr < 2; ++rr) {
        const int r = rbase + rr;
        const int b = r & (B - 1), t = r >> 6;    // r = t*B + b
        const float* rw = rows[w][rr];
        const int lab_len = label_lens[b];
        const int off     = offsets[b];
        const float ubk   = rw[0];
        const int j0 = 4 * lane;
        float q0 = (j0 + 0 < lab_len) ? rw[labels[min(off + j0 + 0, B * L - 1)]] : ubk;
        float q1 = (j0 + 1 < lab_len) ? rw[labels[min(off + j0 + 1, B * L - 1)]] : ubk;
        float q2 = (j0 + 2 < lab_len) ? rw[labels[min(off + j0 + 2, B * L - 1)]] : ubk;
        float q3 = (j0 + 3 < lab_len) ? rw[labels[min(off + j0 + 3, B * L - 1)]] : ubk;
        ushort4 hv = {f2bf(q0), f2bf(q1), f2bf(q2), f2bf(q3)};
        ((ushort4*)packedU)[(size_t)(b * T + t) * 64 + lane] = hv;
        if (lane == 0) {
            lse_rows[b * T + t] = __logf(rr ? sb : sa);
            blankU[b * T + t]   = ubk;
        }
    }
}

// ---------------------------------------------------------------------------
// Fwd/bwd linear-space CTC scan, register-resident chunks, all-VALU steps.
// R9 post-mortem: VGPR_Count=88 < 96 (3 buffers) proved LLVM sank each
// global_load to its single use -> one full vmcnt latency PER STEP (~220
// cyc/step). Fix: zero-inst asm pins (`"+v"`) on every chunk dword placed
// immediately BEFORE that chunk's compute. The pin is the point-of-demand:
// loads can sink at most to it (issued 1-2 full chunk-computes earlier, so
// latency covered), and after it the values are register definitions the
// steps read directly. Expect VGPR >= 150 as the signature this worked.
// ---------------------------------------------------------------------------
__global__ __launch_bounds__(128, 1) void ctc_kernel(
    const int* __restrict__ labels, const int* __restrict__ act_lens,
    const int* __restrict__ label_lens, const int* __restrict__ offsets,
    const float* __restrict__ lse_rows, const unsigned short* __restrict__ packedU,
    const float* __restrict__ blankU, float* __restrict__ out)
{
    __shared__ float sbr[S];
    __shared__ float s_accb;

    const int b    = blockIdx.x;
    const int wave = threadIdx.x >> 6;
    const int lane = threadIdx.x & 63;
    const int lab_len = label_lens[b];
    const int a_len   = act_lens[b];
    const int th      = (a_len - 1) >> 1;
    const int thp1    = th + 1;
    const int off     = offsets[b];
    const size_t rowbase = (size_t)b * T;

    int li0 = 4 * lane;
    int eprev = (li0 - 1 >= 0 && li0 - 1 < lab_len) ? labels[min(off + li0 - 1, B * L - 1)] : 0;
    int enext = (li0 + 4 < lab_len) ? labels[min(off + li0 + 4, B * L - 1)] : 0;
    int e0 = (li0 + 0 < lab_len) ? labels[min(off + li0 + 0, B * L - 1)] : 0;
    int e1 = (li0 + 1 < lab_len) ? labels[min(off + li0 + 1, B * L - 1)] : 0;
    int e2 = (li0 + 2 < lab_len) ? labels[min(off + li0 + 2, B * L - 1)] : 0;
    int e3 = (li0 + 3 < lab_len) ? labels[min(off + li0 + 3, B * L - 1)] : 0;

    // skip-allow flags for odd states 8l+1,3,5,7 (same for fwd & bwd mappings)
    const float aF0 = (8 * lane + 1 >= 2 && e0 != 0 && e0 != eprev) ? 1.f : 0.f;
    const float aF1 = (e1 != 0 && e1 != e0) ? 1.f : 0.f;
    const float aF2 = (e2 != 0 && e2 != e1) ? 1.f : 0.f;
    const float aF3 = (e3 != 0 && e3 != e2) ? 1.f : 0.f;
    const float aB0 = aF1, aB1 = aF2, aB2 = aF3;
    const float aB3 = (enext != 0 && enext != e3) ? 1.f : 0.f;

    float A0 = 0.f, A1 = 0.f, A2 = 0.f, A3 = 0.f, A4 = 0.f,
          A5 = 0.f, A6 = 0.f, A7 = 0.f, A8 = 0.f;
    float acc = 0.f, sls = 0.f;

    uint2 U0[C], U1[C], U2[C];      // static-indexed -> registers (pinned)
    float K0 = 0.f, K1 = 0.f, K2 = 0.f;  // blank rows: lane (i&15) holds row i

#define PINV(x) asm volatile("" : "+v"(x))
#define PINCH(U, K) do {                                                      \
        _Pragma("unroll")                                                     \
        for (int i_ = 0; i_ < C; ++i_) { PINV(U[i_].x); PINV(U[i_].y); }      \
        PINV(K);                                                              \
    } while (0)

#define LOADCH(U, K, TLO) do {                                                \
        const int tl_ = min(max((int)(TLO), 0), T - C);                       \
        const uint2* gp_ = (const uint2*)(packedU + (rowbase + tl_) * 256);   \
        _Pragma("unroll")                                                     \
        for (int i_ = 0; i_ < C; ++i_) U[i_] = gp_[i_ * 64 + lane];           \
        K = blankU[rowbase + tl_ + (lane & (C - 1))];                         \
    } while (0)

#define RESCALE() do {                                                        \
        float m_ = fmaxf(A8, A0); m_ = fmaxf(m_, A1); m_ = fmaxf(m_, A2);     \
        m_ = fmaxf(m_, A3); m_ = fmaxf(m_, A4); m_ = fmaxf(m_, A5);           \
        m_ = fmaxf(m_, A6); m_ = fmaxf(m_, A7);                               \
        m_ = dppmax<0x111, 0xf>(m_);  /* row_shr:1 */                         \
        m_ = dppmax<0x112, 0xf>(m_);  /* row_shr:2 */                         \
        m_ = dppmax<0x114, 0xf>(m_);  /* row_shr:4 */                         \
        m_ = dppmax<0x118, 0xf>(m_);  /* row_shr:8 */                         \
        m_ = dppmax<0x142, 0xa>(m_);  /* bcast15 -> rows 1,3 */               \
        m_ = dppmax<0x143, 0xc>(m_);  /* bcast31 -> rows 2,3 */               \
        m_ = lane_bcast(m_, 63);                                              \
        m_ = fmaxf(m_, 1e-30f);                                               \
        float inv_ = __builtin_amdgcn_rcpf(m_);                               \
        acc += __logf(m_);                                                    \
        A0 *= inv_; A1 *= inv_; A2 *= inv_; A3 *= inv_; A4 *= inv_;           \
        A5 *= inv_; A6 *= inv_; A7 *= inv_; A8 *= inv_;                       \
    } while (0)

    // fwd: lane holds states 8l..8l+7 (A0..A7), A8 = state 512 on lane 63
#define STEPF_CORE(HX, HY, UB) do {                                           \
        const float ub_ = (UB);                                               \
        const unsigned hx_ = (HX), hy_ = (HY);                                \
        const float u0_ = __uint_as_float(hx_ << 16);                         \
        const float u1_ = __uint_as_float(hx_ & 0xffff0000u);                 \
        const float u2_ = __uint_as_float(hy_ << 16);                         \
        const float u3_ = __uint_as_float(hy_ & 0xffff0000u);                 \
        const float pA7_ = dpp_shr1z(A7);                                     \
        A8 = ub_ * (A8 + A7);                                                 \
        A7 = u3_ * fmaf(aF3, A5, A7 + A6);                                    \
        A6 = ub_ * (A6 + A5);                                                 \
        A5 = u2_ * fmaf(aF2, A3, A5 + A4);                                    \
        A4 = ub_ * (A4 + A3);                                                 \
        A3 = u1_ * fmaf(aF1, A1, A3 + A2);                                    \
        A2 = ub_ * (A2 + A1);                                                 \
        A1 = u0_ * fmaf(aF0, pA7_, A1 + A0);                                  \
        A0 = ub_ * (A0 + pA7_);                                               \
    } while (0)
#define STEPF_R(U, K, I) STEPF_CORE(U[I].x, U[I].y, lane_bcast(K, I))

    // bwd: lane holds states 8l+1..8l+8 (A0..A7), A8 = state 0 on lane 0.
    // Needs only the neighbor's lowest state (s=8l+9) -> ONE dpp shift.
#define STEPB_CORE(HX, HY, UB) do {                                           \
        const float ub_ = (UB);                                               \
        const unsigned hx_ = (HX), hy_ = (HY);                                \
        const float u0_ = __uint_as_float(hx_ << 16);                         \
        const float u1_ = __uint_as_float(hx_ & 0xffff0000u);                 \
        const float u2_ = __uint_as_float(hy_ << 16);                         \
        const float u3_ = __uint_as_float(hy_ & 0xffff0000u);                 \
        const float nC0_ = dpp_shl1z(A0);                                     \
        A8 = ub_ * (A8 + A0);                                                 \
        A0 = u0_ * fmaf(aB0, A2, A0 + A1);                                    \
        A1 = ub_ * (A1 + A2);                                                 \
        A2 = u1_ * fmaf(aB1, A4, A2 + A3);                                    \
        A3 = ub_ * (A3 + A4);                                                 \
        A4 = u2_ * fmaf(aB2, A6, A4 + A5);                                    \
        A5 = ub_ * (A5 + A6);                                                 \
        A6 = u3_ * fmaf(aB3, nC0_, A6 + A7);                                  \
        A7 = ub_ * (A7 + nC0_);                                               \
    } while (0)
#define STEPB_R(U, K, I) STEPB_CORE(U[I].x, U[I].y, lane_bcast(K, I))

#define STEP_DIRECT(WHICH, TT) do {                                           \
        uint2 hvd_ = ((const uint2*)(packedU + (rowbase + (TT)) * 256))[lane];\
        float ubd_ = blankU[rowbase + (TT)];                                  \
        WHICH(hvd_.x, hvd_.y, ubd_);                                          \
    } while (0)

#define DOF16(U, K) do {                                                      \
        _Pragma("unroll")                                                     \
        for (int i_ = 0; i_ < C; ++i_) {                                      \
            STEPF_R(U, K, i_);                                                \
            if (i_ == 7 || i_ == 15) RESCALE();                               \
        }                                                                     \
    } while (0)
#define DOFPART(U, K, TLO) do {                                               \
        _Pragma("unroll")                                                     \
        for (int i_ = 0; i_ < C; ++i_) {                                      \
            if ((TLO) + i_ <= th) STEPF_R(U, K, i_);                          \
            if (i_ == 7 || i_ == 15) RESCALE();                               \
        }                                                                     \
    } while (0)
#define DOB16(U, K) do {                                                      \
        _Pragma("unroll")                                                     \
        for (int i_ = C - 1; i_ >= 0; --i_) {                                 \
            STEPB_R(U, K, i_);                                                \
            if (i_ == 8 || i_ == 0) RESCALE();                                \
        }                                                                     \
    } while (0)
#define DOBPART(U, K, TLO) do {                                               \
        _Pragma("unroll")                                                     \
        for (int i_ = C - 1; i_ >= 0; --i_) {                                 \
            if ((TLO) + i_ >= thp1) STEPB_R(U, K, i_);                        \
            if (i_ == 8 || i_ == 0) RESCALE();                                \
        }                                                                     \
    } while (0)

    if (wave == 0) {
        if (lane == 0) {
            A0 = blankU[rowbase];
            A1 = __uint_as_float(((unsigned)packedU[rowbase * 256]) << 16);
        }

        if (th >= 1) {
            const int nst   = th;           // steps t = 1..th, chunk c: tlo=1+16c
            const int nc    = (nst + C - 1) / C;
            const int nfull = nst / C;
            LOADCH(U0, K0, 1);
            LOADCH(U1, K1, 1 + C);
            LOADCH(U2, K2, 1 + 2 * C);

            // lse sum overlaps the first chunk's load latency
            for (int t = lane; t < a_len; t += 64) sls += lse_rows[rowbase + t];
#pragma unroll
            for (int o = 32; o; o >>= 1) sls += __shfl_xor(sls, o, 64);

            int c = 0;
            for (; c + 3 <= nfull; c += 3) {
                PINCH(U0, K0); DOF16(U0, K0); LOADCH(U0, K0, 1 + C * (c + 3));
                PINCH(U1, K1); DOF16(U1, K1); LOADCH(U1, K1, 1 + C * (c + 4));
                PINCH(U2, K2); DOF16(U2, K2); LOADCH(U2, K2, 1 + C * (c + 5));
            }
            const int rem = nfull - c;
            if (rem == 0) {
                if (nc > nfull) { PINCH(U0, K0); DOFPART(U0, K0, 1 + C * c); }
            } else if (rem == 1) {
                PINCH(U0, K0); DOF16(U0, K0);
                if (nc > nfull) { PINCH(U1, K1); DOFPART(U1, K1, 1 + C * (c + 1)); }
            } else {
                PINCH(U0, K0); DOF16(U0, K0);
                PINCH(U1, K1); DOF16(U1, K1);
                if (nc > nfull) { PINCH(U2, K2); DOFPART(U2, K2, 1 + C * (c + 2)); }
            }
        } else {
            for (int t = lane; t < a_len; t += 64) sls += lse_rows[rowbase + t];
#pragma unroll
            for (int o = 32; o; o >>= 1) sls += __shfl_xor(sls, o, 64);
        }
    } else {
        const int send = 2 * lab_len;
        {
            size_t rl = rowbase + (a_len - 1);
            float ubl = blankU[rl];
            float ue  = (lab_len > 0)
                      ? __uint_as_float(((unsigned)packedU[rl * 256 + (lab_len - 1)]) << 16)
                      : 0.f;
            int s0 = 8 * lane + 1;                  // states s0..s0+7
            A0 = (s0 + 0 == send) ? ubl : ((s0 + 0 == send - 1) ? ue : 0.f);
            A1 = (s0 + 1 == send) ? ubl : ((s0 + 1 == send - 1) ? ue : 0.f);
            A2 = (s0 + 2 == send) ? ubl : ((s0 + 2 == send - 1) ? ue : 0.f);
            A3 = (s0 + 3 == send) ? ubl : ((s0 + 3 == send - 1) ? ue : 0.f);
            A4 = (s0 + 4 == send) ? ubl : ((s0 + 4 == send - 1) ? ue : 0.f);
            A5 = (s0 + 5 == send) ? ubl : ((s0 + 5 == send - 1) ? ue : 0.f);
            A6 = (s0 + 6 == send) ? ubl : ((s0 + 6 == send - 1) ? ue : 0.f);
            A7 = (s0 + 7 == send) ? ubl : ((s0 + 7 == send - 1) ? ue : 0.f);
            A8 = (send == 0) ? ubl : 0.f;           // state 0 (lane 0's only used)
        }

        const int nstB = a_len - 2 - th;            // steps t = a_len-2 .. th+1
        if (nstB > 0 && a_len >= 17) {
            // chunk c: tlo = a_len-17-16c, rows tlo..tlo+15 = steps (desc)
            const int nc    = (nstB + C - 1) / C;
            const int nfull = nstB / C;
            LOADCH(U0, K0, a_len - 17);
            LOADCH(U1, K1, a_len - 17 - C);
            LOADCH(U2, K2, a_len - 17 - 2 * C);
            int c = 0;
            for (; c + 3 <= nfull; c += 3) {
                PINCH(U0, K0); DOB16(U0, K0); LOADCH(U0, K0, a_len - 17 - C * (c + 3));
                PINCH(U1, K1); DOB16(U1, K1); LOADCH(U1, K1, a_len - 17 - C * (c + 4));
                PINCH(U2, K2); DOB16(U2, K2); LOADCH(U2, K2, a_len - 17 - C * (c + 5));
            }
            const int rem = nfull - c;
            if (rem == 0) {
                if (nc > nfull) { PINCH(U0, K0); DOBPART(U0, K0, a_len - 17 - C * c); }
            } else if (rem == 1) {
                PINCH(U0, K0); DOB16(U0, K0);
                if (nc > nfull) { PINCH(U1, K1); DOBPART(U1, K1, a_len - 17 - C * (c + 1)); }
            } else {
                PINCH(U0, K0); DOB16(U0, K0);
                PINCH(U1, K1); DOB16(U1, K1);
                if (nc > nfull) { PINCH(U2, K2); DOBPART(U2, K2, a_len - 17 - C * (c + 2)); }
            }
        } else if (nstB > 0) {                      // tiny a_len fallback
            for (int t = a_len - 2; t >= thp1; --t) {
                STEP_DIRECT(STEPB_CORE, t);
                if (((a_len - 2 - t) & 7) == 7) RESCALE();
            }
        }

        {   // bracket W(s) = B(s) + B(s+1) + allow(s+2)*B(s+2), B = beta_{th+1}
            float nC0 = dpp_shl1z(A0);
            float w1 = fmaf(aB0, A2, A0 + A1);      // s = 8l+1
            float w2 = A1 + A2;                     // s = 8l+2
            float w3 = fmaf(aB1, A4, A2 + A3);      // s = 8l+3
            float w4 = A3 + A4;                     // s = 8l+4
            float w5 = fmaf(aB2, A6, A4 + A5);      // s = 8l+5
            float w6 = A5 + A6;                     // s = 8l+6
            float w7 = fmaf(aB3, nC0, A6 + A7);     // s = 8l+7
            float w8 = A7 + nC0;                    // s = 8l+8
            int sB = 8 * lane + 1;
            sbr[sB + 0] = w1; sbr[sB + 1] = w2; sbr[sB + 2] = w3; sbr[sB + 3] = w4;
            sbr[sB + 4] = w5; sbr[sB + 5] = w6; sbr[sB + 6] = w7; sbr[sB + 7] = w8;
            if (lane == 0) sbr[0] = A8 + A0;        // W(0) = B(0) + B(1)
            if (lane == 0) s_accb = acc;
        }
    }
    __syncthreads();
    if (wave == 0) {
        // LOG-space junction (linear dot of the two independently-rescaled
        // sides underflows fp32)
        int s0 = 8 * lane;
        float p0 = __logf(fmaxf(A0, 1e-37f)) + __logf(fmaxf(sbr[s0 + 0], 1e-37f));
        float p1 = __logf(fmaxf(A1, 1e-37f)) + __logf(fmaxf(sbr[s0 + 1], 1e-37f));
        float p2 = __logf(fmaxf(A2, 1e-37f)) + __logf(fmaxf(sbr[s0 + 2], 1e-37f));
        float p3 = __logf(fmaxf(A3, 1e-37f)) + __logf(fmaxf(sbr[s0 + 3], 1e-37f));
        float p4 = __logf(fmaxf(A4, 1e-37f)) + __logf(fmaxf(sbr[s0 + 4], 1e-37f));
        float p5 = __logf(fmaxf(A5, 1e-37f)) + __logf(fmaxf(sbr[s0 + 5], 1e-37f));
        float p6 = __logf(fmaxf(A6, 1e-37f)) + __logf(fmaxf(sbr[s0 + 6], 1e-37f));
        float p7 = __logf(fmaxf(A7, 1e-37f)) + __logf(fmaxf(sbr[s0 + 7], 1e-37f));
        float p8 = -3.0e38f;
        if (lane == 63) p8 = __logf(fmaxf(A8, 1e-37f)) + __logf(fmaxf(sbr[512], 1e-37f));
        float pmax = fmaxf(fmaxf(fmaxf(p0, p1), fmaxf(p2, p3)),
                           fmaxf(fmaxf(p4, p5), fmaxf(p6, p7)));
        pmax = fmaxf(pmax, p8);
#pragma unroll
        for (int o = 32; o; o >>= 1) pmax = fmaxf(pmax, __shfl_xor(pmax, o, 64));
        float dot = __expf(p0 - pmax) + __expf(p1 - pmax) + __expf(p2 - pmax)
                  + __expf(p3 - pmax) + __expf(p4 - pmax) + __expf(p5 - pmax)
                  + __expf(p6 - pmax) + __expf(p7 - pmax);
        if (lane == 63) dot += __expf(p8 - pmax);
#pragma unroll
        for (int o = 32; o; o >>= 1) dot += __shfl_xor(dot, o, 64);
        if (lane == 0) {
            float loss = sls - acc - s_accb - (pmax + __logf(dot));
            atomicAdd(out, loss);
        }
    }
#undef PINV
#undef PINCH
#undef LOADCH
#undef RESCALE
#undef STEPF_CORE
#undef STEPF_R
#undef STEPB_CORE
#undef STEPB_R
#undef STEP_DIRECT
#undef DOF16
#undef DOFPART
#undef DOB16
#undef DOBPART
}

extern "C" void kernel_launch(void* const* d_in, const int* in_sizes, int n_in,
                              void* d_out, int out_size, void* d_ws, size_t ws_size,
                              hipStream_t stream) {
    const float* acts       = (const float*)d_in[0];
    const int*   labels     = (const int*)d_in[1];
    const int*   act_lens   = (const int*)d_in[2];
    const int*   label_lens = (const int*)d_in[3];
    float*       out        = (float*)d_out;

    float*          lse_rows = (float*)d_ws;
    float*          blankU   = (float*)((char*)d_ws + (size_t)T * B * 4);
    int*            offsets  = (int*)  ((char*)d_ws + (size_t)2 * T * B * 4);
    unsigned short* packedU  = (unsigned short*)((char*)d_ws + (1u << 20));

    hipMemsetAsync(d_out, 0, sizeof(float), stream);

    offsets_kernel<<<1, 64, 0, stream>>>(label_lens, offsets);
    setup_kernel<<<T * B / 8, 256, 0, stream>>>(
        acts, labels, label_lens, offsets, lse_rows, packedU, blankU);
    ctc_kernel<<<B, 128, 0, stream>>>(
        labels, act_lens, label_lens, offsets, lse_rows, packedU, blankU, out);
}

// Round 5
// 243.756 us; speedup vs baseline: 1.1461x; 1.0100x over previous
//
#include <hip/hip_runtime.h>

constexpr int T = 1024;
constexpr int B = 64;
constexpr int V = 512;
constexpr int L = 256;
constexpr int S = 2 * L + 1;   // 513
constexpr int C = 16;          // scan chunk rows (128 B/lane, register-resident)

typedef float f32x4 __attribute__((ext_vector_type(4)));

__device__ __forceinline__ unsigned short f2bf(float f) {  // RNE
    unsigned u = __float_as_uint(f);
    u += 0x7fffu + ((u >> 16) & 1u);
    return (unsigned short)(u >> 16);
}

__device__ __forceinline__ float lane_bcast(float v, int i) {
    return __uint_as_float((unsigned)__builtin_amdgcn_readlane((int)__float_as_uint(v), i));
}

// DPP lane shifts: pure VALU (no lgkm). Direction per LLVM AtomicOptimizer:
// WAVE_SHR1 (0x138): lane n <- lane n-1 (== __shfl_up by 1), lane 0 -> 0.
// WAVE_SHL1 (0x130): lane n <- lane n+1 (== __shfl_down by 1), lane 63 -> 0.
__device__ __forceinline__ float dpp_shr1z(float x) {
    return __uint_as_float((unsigned)__builtin_amdgcn_update_dpp(
        0, (int)__float_as_uint(x), 0x138, 0xf, 0xf, true));
}
__device__ __forceinline__ float dpp_shl1z(float x) {
    return __uint_as_float((unsigned)__builtin_amdgcn_update_dpp(
        0, (int)__float_as_uint(x), 0x130, 0xf, 0xf, true));
}
// one level of a DPP max-reduce ladder (masked lanes keep old = identity)
template <int CTRL, int RM>
__device__ __forceinline__ float dppmax(float m) {
    int mi = (int)__float_as_uint(m);
    int t = __builtin_amdgcn_update_dpp(mi, mi, CTRL, RM, 0xf, false);
    return fmaxf(m, __uint_as_float((unsigned)t));
}
// one level of a DPP add-reduce ladder (old=0, bound_ctrl=1 -> masked/invalid
// lanes contribute +0 = identity)
template <int CTRL, int RM>
__device__ __forceinline__ float dppadd(float m) {
    int mi = (int)__float_as_uint(m);
    int t = __builtin_amdgcn_update_dpp(0, mi, CTRL, RM, 0xf, true);
    return m + __uint_as_float((unsigned)t);
}
// full wave64 ladders: total lands on lane 63
#define DPPMAX_LADDER(m) do {                                                 \
        m = dppmax<0x111, 0xf>(m); m = dppmax<0x112, 0xf>(m);                 \
        m = dppmax<0x114, 0xf>(m); m = dppmax<0x118, 0xf>(m);                 \
        m = dppmax<0x142, 0xa>(m); m = dppmax<0x143, 0xc>(m);                 \
    } while (0)
#define DPPADD_LADDER(m) do {                                                 \
        m = dppadd<0x111, 0xf>(m); m = dppadd<0x112, 0xf>(m);                 \
        m = dppadd<0x114, 0xf>(m); m = dppadd<0x118, 0xf>(m);                 \
        m = dppadd<0x142, 0xa>(m); m = dppadd<0x143, 0xc>(m);                 \
    } while (0)

// ws layout (batch-major):
// [0]      lse_rows : B*T floats (256 KB)   [b*T+t]
// [256K]   blankU   : B*T floats (256 KB)   [b*T+t]  exp(blank logit)
// [512K]   offsets  : B ints
// [1M]     packedU  : B*T*256 bf16 (32 MB)  [(b*T+t)*256+j] exp(label logits)

__global__ __launch_bounds__(64) void offsets_kernel(
    const int* __restrict__ label_lens, int* __restrict__ offsets)
{
    int lane = threadIdx.x;
    int v = (lane < B) ? label_lens[lane] : 0;
    int x = v;
#pragma unroll
    for (int o = 1; o < 64; o <<= 1) {
        int y = __shfl_up(x, o, 64);
        if (lane >= o) x += y;
    }
    if (lane < B) offsets[lane] = x - v;
}

// ---------------------------------------------------------------------------
// Setup: one wave per TWO (t,b) rows. exp the rows once; emit row-lse + bf16
// exp(label logits) + blank, all in BATCH-MAJOR layout.
// ---------------------------------------------------------------------------
__global__ __launch_bounds__(256) void setup_kernel(
    const float* __restrict__ acts, const int* __restrict__ labels,
    const int* __restrict__ label_lens, const int* __restrict__ offsets,
    float* __restrict__ lse_rows, unsigned short* __restrict__ packedU,
    float* __restrict__ blankU)
{
    __shared__ float rows[4][2][V];          // 16 KB
    const int w    = threadIdx.x >> 6;
    const int lane = threadIdx.x & 63;
    const int rbase = (blockIdx.x * 4 + w) * 2;     // rows rbase, rbase+1
    const f32x4* p = (const f32x4*)(acts + (size_t)rbase * V);

    f32x4 xa0 = __builtin_nontemporal_load(p + lane);
    f32x4 xa1 = __builtin_nontemporal_load(p + lane + 64);
    f32x4 xb0 = __builtin_nontemporal_load(p + lane + 128);
    f32x4 xb1 = __builtin_nontemporal_load(p + lane + 192);
    f32x4 ea0, ea1, eb0, eb1;
    ea0.x=__expf(xa0.x); ea0.y=__expf(xa0.y); ea0.z=__expf(xa0.z); ea0.w=__expf(xa0.w);
    ea1.x=__expf(xa1.x); ea1.y=__expf(xa1.y); ea1.z=__expf(xa1.z); ea1.w=__expf(xa1.w);
    eb0.x=__expf(xb0.x); eb0.y=__expf(xb0.y); eb0.z=__expf(xb0.z); eb0.w=__expf(xb0.w);
    eb1.x=__expf(xb1.x); eb1.y=__expf(xb1.y); eb1.z=__expf(xb1.z); eb1.w=__expf(xb1.w);
    ((f32x4*)rows[w][0])[lane]      = ea0;
    ((f32x4*)rows[w][0])[lane + 64] = ea1;
    ((f32x4*)rows[w][1])[lane]      = eb0;
    ((f32x4*)rows[w][1])[lane + 64] = eb1;
    float sa = ea0.x+ea0.y+ea0.z+ea0.w + ea1.x+ea1.y+ea1.z+ea1.w;
    float sb = eb0.x+eb0.y+eb0.z+eb0.w + eb1.x+eb1.y+eb1.z+eb1.w;
#pragma unroll
    for (int o = 32; o; o >>= 1) { sa += __shfl_xor(sa, o, 64); sb += __shfl_xor(sb, o, 64); }

#pragma unroll
    for (int rr = 0; rr < 2; ++rr) {
        const int r = rbase + rr;
        const int b = r & (B - 1), t = r >> 6;    // r = t*B + b
        const float* rw = rows[w][rr];
        const int lab_len = label_lens[b];
        const int off     = offsets[b];
        const float ubk   = rw[0];
        const int j0 = 4 * lane;
        float q0 = (j0 + 0 < lab_len) ? rw[labels[min(off + j0 + 0, B * L - 1)]] : ubk;
        float q1 = (j0 + 1 < lab_len) ? rw[labels[min(off + j0 + 1, B * L - 1)]] : ubk;
        float q2 = (j0 + 2 < lab_len) ? rw[labels[min(off + j0 + 2, B * L - 1)]] : ubk;
        float q3 = (j0 + 3 < lab_len) ? rw[labels[min(off + j0 + 3, B * L - 1)]] : ubk;
        ushort4 hv = {f2bf(q0), f2bf(q1), f2bf(q2), f2bf(q3)};
        ((ushort4*)packedU)[(size_t)(b * T + t) * 64 + lane] = hv;
        if (lane == 0) {
            lse_rows[b * T + t] = __logf(rr ? sb : sa);
            blankU[b * T + t]   = ubk;
        }
    }
}

// ---------------------------------------------------------------------------
// Fwd/bwd linear-space CTC scan, all-VALU steps, NAMED-SCALAR chunk buffers.
// R10 post-mortem chain: R3 removed all per-step lgkm (DPP) for only -4us,
// and R4's pins were exactly neutral -> the ~150cyc/step stall is a per-step
// MEMORY access that hides shuffle latency: the uint2 U[16] array buffers
// living in SCRATCH (rule #20: array promotion is fragile under macro-pragma
// unroll + asm-on-element). Fix by construction: 48 named uint2 scalars
// (a_0..c_15, a_K..c_K), token-pasted literal indices everywhere - scratch
// impossible. Triple-buffered rotation, one vmcnt wait per chunk, issued 2
// chunk-computes (~1800cyc) ahead. Also: fwd sls loop vectorized (4xf32x4 +
// DPP-add ladder) and epilogue shfl ladders -> DPP ladders.
// ---------------------------------------------------------------------------
__global__ __launch_bounds__(128, 1) void ctc_kernel(
    const int* __restrict__ labels, const int* __restrict__ act_lens,
    const int* __restrict__ label_lens, const int* __restrict__ offsets,
    const float* __restrict__ lse_rows, const unsigned short* __restrict__ packedU,
    const float* __restrict__ blankU, float* __restrict__ out)
{
    __shared__ float sbr[S];
    __shared__ float s_accb;

    const int b    = blockIdx.x;
    const int wave = threadIdx.x >> 6;
    const int lane = threadIdx.x & 63;
    const int lab_len = label_lens[b];
    const int a_len   = act_lens[b];
    const int th      = (a_len - 1) >> 1;
    const int thp1    = th + 1;
    const int off     = offsets[b];
    const size_t rowbase = (size_t)b * T;

    int li0 = 4 * lane;
    int eprev = (li0 - 1 >= 0 && li0 - 1 < lab_len) ? labels[min(off + li0 - 1, B * L - 1)] : 0;
    int enext = (li0 + 4 < lab_len) ? labels[min(off + li0 + 4, B * L - 1)] : 0;
    int e0 = (li0 + 0 < lab_len) ? labels[min(off + li0 + 0, B * L - 1)] : 0;
    int e1 = (li0 + 1 < lab_len) ? labels[min(off + li0 + 1, B * L - 1)] : 0;
    int e2 = (li0 + 2 < lab_len) ? labels[min(off + li0 + 2, B * L - 1)] : 0;
    int e3 = (li0 + 3 < lab_len) ? labels[min(off + li0 + 3, B * L - 1)] : 0;

    // skip-allow flags for odd states 8l+1,3,5,7 (same for fwd & bwd mappings)
    const float aF0 = (8 * lane + 1 >= 2 && e0 != 0 && e0 != eprev) ? 1.f : 0.f;
    const float aF1 = (e1 != 0 && e1 != e0) ? 1.f : 0.f;
    const float aF2 = (e2 != 0 && e2 != e1) ? 1.f : 0.f;
    const float aF3 = (e3 != 0 && e3 != e2) ? 1.f : 0.f;
    const float aB0 = aF1, aB1 = aF2, aB2 = aF3;
    const float aB3 = (enext != 0 && enext != e3) ? 1.f : 0.f;

    float A0 = 0.f, A1 = 0.f, A2 = 0.f, A3 = 0.f, A4 = 0.f,
          A5 = 0.f, A6 = 0.f, A7 = 0.f, A8 = 0.f;
    float acc = 0.f, sls = 0.f;

    // NAMED scalar chunk buffers (no arrays -> no scratch, ever)
    uint2 a_0,a_1,a_2,a_3,a_4,a_5,a_6,a_7,a_8,a_9,a_10,a_11,a_12,a_13,a_14,a_15;
    uint2 b_0,b_1,b_2,b_3,b_4,b_5,b_6,b_7,b_8,b_9,b_10,b_11,b_12,b_13,b_14,b_15;
    uint2 c_0,c_1,c_2,c_3,c_4,c_5,c_6,c_7,c_8,c_9,c_10,c_11,c_12,c_13,c_14,c_15;
    float a_K = 0.f, b_K = 0.f, c_K = 0.f;  // blank rows: lane (i&15) holds row i

#define PINV(x) asm volatile("" : "+v"(x))
#define APPLY16(M, P) M(P,0) M(P,1) M(P,2) M(P,3) M(P,4) M(P,5) M(P,6) M(P,7) \
                      M(P,8) M(P,9) M(P,10) M(P,11) M(P,12) M(P,13) M(P,14) M(P,15)

#define LD1(P, I) P##_##I = gp_[(I) * 64 + lane];
#define LOADCH(P, TLO) do {                                                   \
        const int tl_ = min(max((int)(TLO), 0), T - C);                       \
        const uint2* gp_ = (const uint2*)(packedU + (rowbase + tl_) * 256);   \
        APPLY16(LD1, P)                                                       \
        P##_K = blankU[rowbase + tl_ + (lane & (C - 1))];                     \
    } while (0)

#define PIN1(P, I) PINV(P##_##I.x); PINV(P##_##I.y);
#define PINCH(P) do { APPLY16(PIN1, P) PINV(P##_K); } while (0)

#define RESCALE() do {                                                        \
        float m_ = fmaxf(A8, A0); m_ = fmaxf(m_, A1); m_ = fmaxf(m_, A2);     \
        m_ = fmaxf(m_, A3); m_ = fmaxf(m_, A4); m_ = fmaxf(m_, A5);           \
        m_ = fmaxf(m_, A6); m_ = fmaxf(m_, A7);                               \
        DPPMAX_LADDER(m_);                                                    \
        m_ = lane_bcast(m_, 63);                                              \
        m_ = fmaxf(m_, 1e-30f);                                               \
        float inv_ = __builtin_amdgcn_rcpf(m_);                               \
        acc += __logf(m_);                                                    \
        A0 *= inv_; A1 *= inv_; A2 *= inv_; A3 *= inv_; A4 *= inv_;           \
        A5 *= inv_; A6 *= inv_; A7 *= inv_; A8 *= inv_;                       \
    } while (0)

    // fwd: lane holds states 8l..8l+7 (A0..A7), A8 = state 512 on lane 63
#define STEPF_CORE(HX, HY, UB) do {                                           \
        const float ub_ = (UB);                                               \
        const unsigned hx_ = (HX), hy_ = (HY);                                \
        const float u0_ = __uint_as_float(hx_ << 16);                         \
        const float u1_ = __uint_as_float(hx_ & 0xffff0000u);                 \
        const float u2_ = __uint_as_float(hy_ << 16);                         \
        const float u3_ = __uint_as_float(hy_ & 0xffff0000u);                 \
        const float pA7_ = dpp_shr1z(A7);                                     \
        A8 = ub_ * (A8 + A7);                                                 \
        A7 = u3_ * fmaf(aF3, A5, A7 + A6);                                    \
        A6 = ub_ * (A6 + A5);                                                 \
        A5 = u2_ * fmaf(aF2, A3, A5 + A4);                                    \
        A4 = ub_ * (A4 + A3);                                                 \
        A3 = u1_ * fmaf(aF1, A1, A3 + A2);                                    \
        A2 = ub_ * (A2 + A1);                                                 \
        A1 = u0_ * fmaf(aF0, pA7_, A1 + A0);                                  \
        A0 = ub_ * (A0 + pA7_);                                               \
    } while (0)

    // bwd: lane holds states 8l+1..8l+8 (A0..A7), A8 = state 0 on lane 0.
    // Needs only the neighbor's lowest state (s=8l+9) -> ONE dpp shift.
#define STEPB_CORE(HX, HY, UB) do {                                           \
        const float ub_ = (UB);                                               \
        const unsigned hx_ = (HX), hy_ = (HY);                                \
        const float u0_ = __uint_as_float(hx_ << 16);                         \
        const float u1_ = __uint_as_float(hx_ & 0xffff0000u);                 \
        const float u2_ = __uint_as_float(hy_ << 16);                         \
        const float u3_ = __uint_as_float(hy_ & 0xffff0000u);                 \
        const float nC0_ = dpp_shl1z(A0);                                     \
        A8 = ub_ * (A8 + A0);                                                 \
        A0 = u0_ * fmaf(aB0, A2, A0 + A1);                                    \
        A1 = ub_ * (A1 + A2);                                                 \
        A2 = u1_ * fmaf(aB1, A4, A2 + A3);                                    \
        A3 = ub_ * (A3 + A4);                                                 \
        A4 = u2_ * fmaf(aB2, A6, A4 + A5);                                    \
        A5 = ub_ * (A5 + A6);                                                 \
        A6 = u3_ * fmaf(aB3, nC0_, A6 + A7);                                  \
        A7 = ub_ * (A7 + nC0_);                                               \
    } while (0)

#define SF(P, I)  STEPF_CORE(P##_##I.x, P##_##I.y, lane_bcast(P##_K, I));
#define SB(P, I)  STEPB_CORE(P##_##I.x, P##_##I.y, lane_bcast(P##_K, I));
#define SFG(P, I, TLO) if ((TLO) + (I) <= th)   { SF(P, I) }
#define SBG(P, I, TLO) if ((TLO) + (I) >= thp1) { SB(P, I) }

#define DOF16(P) do {                                                         \
        SF(P,0) SF(P,1) SF(P,2) SF(P,3) SF(P,4) SF(P,5) SF(P,6) SF(P,7)       \
        RESCALE();                                                            \
        SF(P,8) SF(P,9) SF(P,10) SF(P,11) SF(P,12) SF(P,13) SF(P,14) SF(P,15) \
        RESCALE();                                                            \
    } while (0)
#define DOFPART(P, TLO) do {                                                  \
        SFG(P,0,TLO) SFG(P,1,TLO) SFG(P,2,TLO) SFG(P,3,TLO)                   \
        SFG(P,4,TLO) SFG(P,5,TLO) SFG(P,6,TLO) SFG(P,7,TLO)                   \
        RESCALE();                                                            \
        SFG(P,8,TLO) SFG(P,9,TLO) SFG(P,10,TLO) SFG(P,11,TLO)                 \
        SFG(P,12,TLO) SFG(P,13,TLO) SFG(P,14,TLO) SFG(P,15,TLO)               \
        RESCALE();                                                            \
    } while (0)
#define DOB16(P) do {                                                         \
        SB(P,15) SB(P,14) SB(P,13) SB(P,12) SB(P,11) SB(P,10) SB(P,9) SB(P,8) \
        RESCALE();                                                            \
        SB(P,7) SB(P,6) SB(P,5) SB(P,4) SB(P,3) SB(P,2) SB(P,1) SB(P,0)       \
        RESCALE();                                                            \
    } while (0)
#define DOBPART(P, TLO) do {                                                  \
        SBG(P,15,TLO) SBG(P,14,TLO) SBG(P,13,TLO) SBG(P,12,TLO)               \
        SBG(P,11,TLO) SBG(P,10,TLO) SBG(P,9,TLO) SBG(P,8,TLO)                 \
        RESCALE();                                                            \
        SBG(P,7,TLO) SBG(P,6,TLO) SBG(P,5,TLO) SBG(P,4,TLO)                   \
        SBG(P,3,TLO) SBG(P,2,TLO) SBG(P,1,TLO) SBG(P,0,TLO)                   \
        RESCALE();                                                            \
    } while (0)

#define STEP_DIRECT(WHICH, TT) do {                                           \
        uint2 hvd_ = ((const uint2*)(packedU + (rowbase + (TT)) * 256))[lane];\
        float ubd_ = blankU[rowbase + (TT)];                                  \
        WHICH(hvd_.x, hvd_.y, ubd_);                                          \
    } while (0)

    if (wave == 0) {
        if (lane == 0) {
            A0 = blankU[rowbase];
            A1 = __uint_as_float(((unsigned)packedU[rowbase * 256]) << 16);
        }

        if (th >= 1) {
            const int nst   = th;           // steps t = 1..th, chunk c: tlo=1+16c
            const int nc    = (nst + C - 1) / C;
            const int nfull = nst / C;
            LOADCH(a, 1);
            LOADCH(b, 1 + C);
            LOADCH(c, 1 + 2 * C);

            // lse sum overlaps the first chunk's load latency
            if (a_len == T) {               // fast path: 4 vector loads + DPP ladder
                const f32x4* lp = (const f32x4*)(lse_rows + rowbase);
                f32x4 s0 = lp[lane], s1 = lp[lane + 64],
                      s2 = lp[lane + 128], s3 = lp[lane + 192];
                float s = s0.x+s0.y+s0.z+s0.w + s1.x+s1.y+s1.z+s1.w
                        + s2.x+s2.y+s2.z+s2.w + s3.x+s3.y+s3.z+s3.w;
                DPPADD_LADDER(s);
                sls = lane_bcast(s, 63);
            } else {
                for (int t = lane; t < a_len; t += 64) sls += lse_rows[rowbase + t];
#pragma unroll
                for (int o = 32; o; o >>= 1) sls += __shfl_xor(sls, o, 64);
            }

            int cc = 0;
            for (; cc + 3 <= nfull; cc += 3) {
                PINCH(a); DOF16(a); LOADCH(a, 1 + C * (cc + 3));
                PINCH(b); DOF16(b); LOADCH(b, 1 + C * (cc + 4));
                PINCH(c); DOF16(c); LOADCH(c, 1 + C * (cc + 5));
            }
            const int rem = nfull - cc;
            if (rem == 0) {
                if (nc > nfull) { PINCH(a); DOFPART(a, 1 + C * cc); }
            } else if (rem == 1) {
                PINCH(a); DOF16(a);
                if (nc > nfull) { PINCH(b); DOFPART(b, 1 + C * (cc + 1)); }
            } else {
                PINCH(a); DOF16(a);
                PINCH(b); DOF16(b);
                if (nc > nfull) { PINCH(c); DOFPART(c, 1 + C * (cc + 2)); }
            }
        } else {
            for (int t = lane; t < a_len; t += 64) sls += lse_rows[rowbase + t];
#pragma unroll
            for (int o = 32; o; o >>= 1) sls += __shfl_xor(sls, o, 64);
        }
    } else {
        const int send = 2 * lab_len;
        {
            size_t rl = rowbase + (a_len - 1);
            float ubl = blankU[rl];
            float ue  = (lab_len > 0)
                      ? __uint_as_float(((unsigned)packedU[rl * 256 + (lab_len - 1)]) << 16)
                      : 0.f;
            int s0 = 8 * lane + 1;                  // states s0..s0+7
            A0 = (s0 + 0 == send) ? ubl : ((s0 + 0 == send - 1) ? ue : 0.f);
            A1 = (s0 + 1 == send) ? ubl : ((s0 + 1 == send - 1) ? ue : 0.f);
            A2 = (s0 + 2 == send) ? ubl : ((s0 + 2 == send - 1) ? ue : 0.f);
            A3 = (s0 + 3 == send) ? ubl : ((s0 + 3 == send - 1) ? ue : 0.f);
            A4 = (s0 + 4 == send) ? ubl : ((s0 + 4 == send - 1) ? ue : 0.f);
            A5 = (s0 + 5 == send) ? ubl : ((s0 + 5 == send - 1) ? ue : 0.f);
            A6 = (s0 + 6 == send) ? ubl : ((s0 + 6 == send - 1) ? ue : 0.f);
            A7 = (s0 + 7 == send) ? ubl : ((s0 + 7 == send - 1) ? ue : 0.f);
            A8 = (send == 0) ? ubl : 0.f;           // state 0 (lane 0's only used)
        }

        const int nstB = a_len - 2 - th;            // steps t = a_len-2 .. th+1
        if (nstB > 0 && a_len >= 17) {
            // chunk c: tlo = a_len-17-16c, rows tlo..tlo+15 = steps (desc)
            const int nc    = (nstB + C - 1) / C;
            const int nfull = nstB / C;
            LOADCH(a, a_len - 17);
            LOADCH(b, a_len - 17 - C);
            LOADCH(c, a_len - 17 - 2 * C);
            int cc = 0;
            for (; cc + 3 <= nfull; cc += 3) {
                PINCH(a); DOB16(a); LOADCH(a, a_len - 17 - C * (cc + 3));
                PINCH(b); DOB16(b); LOADCH(b, a_len - 17 - C * (cc + 4));
                PINCH(c); DOB16(c); LOADCH(c, a_len - 17 - C * (cc + 5));
            }
            const int rem = nfull - cc;
            if (rem == 0) {
                if (nc > nfull) { PINCH(a); DOBPART(a, a_len - 17 - C * cc); }
            } else if (rem == 1) {
                PINCH(a); DOB16(a);
                if (nc > nfull) { PINCH(b); DOBPART(b, a_len - 17 - C * (cc + 1)); }
            } else {
                PINCH(a); DOB16(a);
                PINCH(b); DOB16(b);
                if (nc > nfull) { PINCH(c); DOBPART(c, a_len - 17 - C * (cc + 2)); }
            }
        } else if (nstB > 0) {                      // tiny a_len fallback
            for (int t = a_len - 2; t >= thp1; --t) {
                STEP_DIRECT(STEPB_CORE, t);
                if (((a_len - 2 - t) & 7) == 7) RESCALE();
            }
        }

        {   // bracket W(s) = B(s) + B(s+1) + allow(s+2)*B(s+2), B = beta_{th+1}
            float nC0 = dpp_shl1z(A0);
            float w1 = fmaf(aB0, A2, A0 + A1);      // s = 8l+1
            float w2 = A1 + A2;                     // s = 8l+2
            float w3 = fmaf(aB1, A4, A2 + A3);      // s = 8l+3
            float w4 = A3 + A4;                     // s = 8l+4
            float w5 = fmaf(aB2, A6, A4 + A5);      // s = 8l+5
            float w6 = A5 + A6;                     // s = 8l+6
            float w7 = fmaf(aB3, nC0, A6 + A7);     // s = 8l+7
            float w8 = A7 + nC0;                    // s = 8l+8
            int sB = 8 * lane + 1;
            sbr[sB + 0] = w1; sbr[sB + 1] = w2; sbr[sB + 2] = w3; sbr[sB + 3] = w4;
            sbr[sB + 4] = w5; sbr[sB + 5] = w6; sbr[sB + 6] = w7; sbr[sB + 7] = w8;
            if (lane == 0) sbr[0] = A8 + A0;        // W(0) = B(0) + B(1)
            if (lane == 0) s_accb = acc;
        }
    }
    __syncthreads();
    if (wave == 0) {
        // LOG-space junction (linear dot of the two independently-rescaled
        // sides underflows fp32)
        int s0 = 8 * lane;
        float p0 = __logf(fmaxf(A0, 1e-37f)) + __logf(fmaxf(sbr[s0 + 0], 1e-37f));
        float p1 = __logf(fmaxf(A1, 1e-37f)) + __logf(fmaxf(sbr[s0 + 1], 1e-37f));
        float p2 = __logf(fmaxf(A2, 1e-37f)) + __logf(fmaxf(sbr[s0 + 2], 1e-37f));
        float p3 = __logf(fmaxf(A3, 1e-37f)) + __logf(fmaxf(sbr[s0 + 3], 1e-37f));
        float p4 = __logf(fmaxf(A4, 1e-37f)) + __logf(fmaxf(sbr[s0 + 4], 1e-37f));
        float p5 = __logf(fmaxf(A5, 1e-37f)) + __logf(fmaxf(sbr[s0 + 5], 1e-37f));
        float p6 = __logf(fmaxf(A6, 1e-37f)) + __logf(fmaxf(sbr[s0 + 6], 1e-37f));
        float p7 = __logf(fmaxf(A7, 1e-37f)) + __logf(fmaxf(sbr[s0 + 7], 1e-37f));
        float p8 = -3.0e38f;
        if (lane == 63) p8 = __logf(fmaxf(A8, 1e-37f)) + __logf(fmaxf(sbr[512], 1e-37f));
        float pmax = fmaxf(fmaxf(fmaxf(p0, p1), fmaxf(p2, p3)),
                           fmaxf(fmaxf(p4, p5), fmaxf(p6, p7)));
        pmax = fmaxf(pmax, p8);
        DPPMAX_LADDER(pmax);
        pmax = lane_bcast(pmax, 63);
        float dot = __expf(p0 - pmax) + __expf(p1 - pmax) + __expf(p2 - pmax)
                  + __expf(p3 - pmax) + __expf(p4 - pmax) + __expf(p5 - pmax)
                  + __expf(p6 - pmax) + __expf(p7 - pmax);
        if (lane == 63) dot += __expf(p8 - pmax);
        DPPADD_LADDER(dot);
        dot = lane_bcast(dot, 63);
        if (lane == 0) {
            float loss = sls - acc - s_accb - (pmax + __logf(dot));
            atomicAdd(out, loss);
        }
    }
#undef PINV
#undef APPLY16
#undef LD1
#undef LOADCH
#undef PIN1
#undef PINCH
#undef RESCALE
#undef STEPF_CORE
#undef STEPB_CORE
#undef SF
#undef SB
#undef SFG
#undef SBG
#undef DOF16
#undef DOFPART
#undef DOB16
#undef DOBPART
#undef STEP_DIRECT
}

extern "C" void kernel_launch(void* const* d_in, const int* in_sizes, int n_in,
                              void* d_out, int out_size, void* d_ws, size_t ws_size,
                              hipStream_t stream) {
    const float* acts       = (const float*)d_in[0];
    const int*   labels     = (const int*)d_in[1];
    const int*   act_lens   = (const int*)d_in[2];
    const int*   label_lens = (const int*)d_in[3];
    float*       out        = (float*)d_out;

    float*          lse_rows = (float*)d_ws;
    float*          blankU   = (float*)((char*)d_ws + (size_t)T * B * 4);
    int*            offsets  = (int*)  ((char*)d_ws + (size_t)2 * T * B * 4);
    unsigned short* packedU  = (unsigned short*)((char*)d_ws + (1u << 20));

    hipMemsetAsync(d_out, 0, sizeof(float), stream);

    offsets_kernel<<<1, 64, 0, stream>>>(label_lens, offsets);
    setup_kernel<<<T * B / 8, 256, 0, stream>>>(
        acts, labels, label_lens, offsets, lse_rows, packedU, blankU);
    ctc_kernel<<<B, 128, 0, stream>>>(
        labels, act_lens, label_lens, offsets, lse_rows, packedU, blankU, out);
}

// Round 6
// 236.102 us; speedup vs baseline: 1.1832x; 1.0324x over previous
//
#include <hip/hip_runtime.h>

constexpr int T = 1024;
constexpr int B = 64;
constexpr int V = 512;
constexpr int L = 256;
constexpr int S = 2 * L + 1;   // 513
constexpr int C = 16;          // scan chunk rows (128 B/lane, register-resident)

typedef float f32x4 __attribute__((ext_vector_type(4)));

__device__ __forceinline__ unsigned short f2bf(float f) {  // RNE
    unsigned u = __float_as_uint(f);
    u += 0x7fffu + ((u >> 16) & 1u);
    return (unsigned short)(u >> 16);
}

__device__ __forceinline__ float lane_bcast(float v, int i) {
    return __uint_as_float((unsigned)__builtin_amdgcn_readlane((int)__float_as_uint(v), i));
}

// DPP lane shifts: pure VALU (no lgkm). Direction per LLVM AtomicOptimizer:
// WAVE_SHR1 (0x138): lane n <- lane n-1 (== __shfl_up by 1), lane 0 -> 0.
// WAVE_SHL1 (0x130): lane n <- lane n+1 (== __shfl_down by 1), lane 63 -> 0.
__device__ __forceinline__ float dpp_shr1z(float x) {
    return __uint_as_float((unsigned)__builtin_amdgcn_update_dpp(
        0, (int)__float_as_uint(x), 0x138, 0xf, 0xf, true));
}
__device__ __forceinline__ float dpp_shl1z(float x) {
    return __uint_as_float((unsigned)__builtin_amdgcn_update_dpp(
        0, (int)__float_as_uint(x), 0x130, 0xf, 0xf, true));
}
// one level of a DPP max-reduce ladder (masked lanes keep old = identity)
template <int CTRL, int RM>
__device__ __forceinline__ float dppmax(float m) {
    int mi = (int)__float_as_uint(m);
    int t = __builtin_amdgcn_update_dpp(mi, mi, CTRL, RM, 0xf, false);
    return fmaxf(m, __uint_as_float((unsigned)t));
}
// one level of a DPP add-reduce ladder (old=0, bound_ctrl=1 -> masked/invalid
// lanes contribute +0 = identity)
template <int CTRL, int RM>
__device__ __forceinline__ float dppadd(float m) {
    int mi = (int)__float_as_uint(m);
    int t = __builtin_amdgcn_update_dpp(0, mi, CTRL, RM, 0xf, true);
    return m + __uint_as_float((unsigned)t);
}
// full wave64 ladders: total lands on lane 63
#define DPPMAX_LADDER(m) do {                                                 \
        m = dppmax<0x111, 0xf>(m); m = dppmax<0x112, 0xf>(m);                 \
        m = dppmax<0x114, 0xf>(m); m = dppmax<0x118, 0xf>(m);                 \
        m = dppmax<0x142, 0xa>(m); m = dppmax<0x143, 0xc>(m);                 \
    } while (0)
#define DPPADD_LADDER(m) do {                                                 \
        m = dppadd<0x111, 0xf>(m); m = dppadd<0x112, 0xf>(m);                 \
        m = dppadd<0x114, 0xf>(m); m = dppadd<0x118, 0xf>(m);                 \
        m = dppadd<0x142, 0xa>(m); m = dppadd<0x143, 0xc>(m);                 \
    } while (0)

// ws layout (batch-major):
// [0]      lse_rows : B*T floats (256 KB)   [b*T+t]
// [256K]   blankU   : B*T floats (256 KB)   [b*T+t]  exp(blank logit)
// [512K]   offsets  : B ints
// [768K]   logub    : B*T floats (256 KB)   [b*T+t]  blank LOGIT (=log u_blank)
// [1M]     packedR  : B*T*256 bf16 (32 MB)  [(b*T+t)*256+j] exp(lab - blank) RATIOS
//
// RATIO REFORMULATION (R11): divide the whole CTC recurrence by prod_t
// u_blank(t). Even-state updates lose their multiply (pure adds), odd states
// multiply by r = u_lab/u_blank, and the factored-out sum of log u_blank over
// t in [1, a_len-2] is a PARALLEL reduction folded into the junction. This
// deletes the per-step v_readlane broadcast (and its VALU->SGPR hazard nops)
// and the blank line of every chunk load.

__global__ __launch_bounds__(64) void offsets_kernel(
    const int* __restrict__ label_lens, int* __restrict__ offsets)
{
    int lane = threadIdx.x;
    int v = (lane < B) ? label_lens[lane] : 0;
    int x = v;
#pragma unroll
    for (int o = 1; o < 64; o <<= 1) {
        int y = __shfl_up(x, o, 64);
        if (lane >= o) x += y;
    }
    if (lane < B) offsets[lane] = x - v;
}

// ---------------------------------------------------------------------------
// Setup: one wave per TWO (t,b) rows. exp the rows once; emit row-lse + bf16
// RATIOS exp(x_lab - x_blank) + blank + raw blank logit, BATCH-MAJOR.
// ---------------------------------------------------------------------------
__global__ __launch_bounds__(256) void setup_kernel(
    const float* __restrict__ acts, const int* __restrict__ labels,
    const int* __restrict__ label_lens, const int* __restrict__ offsets,
    float* __restrict__ lse_rows, unsigned short* __restrict__ packedR,
    float* __restrict__ blankU, float* __restrict__ logub)
{
    __shared__ float rows[4][2][V];          // 16 KB
    const int w    = threadIdx.x >> 6;
    const int lane = threadIdx.x & 63;
    const int rbase = (blockIdx.x * 4 + w) * 2;     // rows rbase, rbase+1
    const f32x4* p = (const f32x4*)(acts + (size_t)rbase * V);

    f32x4 xa0 = __builtin_nontemporal_load(p + lane);
    f32x4 xa1 = __builtin_nontemporal_load(p + lane + 64);
    f32x4 xb0 = __builtin_nontemporal_load(p + lane + 128);
    f32x4 xb1 = __builtin_nontemporal_load(p + lane + 192);
    f32x4 ea0, ea1, eb0, eb1;
    ea0.x=__expf(xa0.x); ea0.y=__expf(xa0.y); ea0.z=__expf(xa0.z); ea0.w=__expf(xa0.w);
    ea1.x=__expf(xa1.x); ea1.y=__expf(xa1.y); ea1.z=__expf(xa1.z); ea1.w=__expf(xa1.w);
    eb0.x=__expf(xb0.x); eb0.y=__expf(xb0.y); eb0.z=__expf(xb0.z); eb0.w=__expf(xb0.w);
    eb1.x=__expf(xb1.x); eb1.y=__expf(xb1.y); eb1.z=__expf(xb1.z); eb1.w=__expf(xb1.w);
    ((f32x4*)rows[w][0])[lane]      = ea0;
    ((f32x4*)rows[w][0])[lane + 64] = ea1;
    ((f32x4*)rows[w][1])[lane]      = eb0;
    ((f32x4*)rows[w][1])[lane + 64] = eb1;
    float sa = ea0.x+ea0.y+ea0.z+ea0.w + ea1.x+ea1.y+ea1.z+ea1.w;
    float sb = eb0.x+eb0.y+eb0.z+eb0.w + eb1.x+eb1.y+eb1.z+eb1.w;
#pragma unroll
    for (int o = 32; o; o >>= 1) { sa += __shfl_xor(sa, o, 64); sb += __shfl_xor(sb, o, 64); }

    const float xblk0 = lane_bcast(xa0.x, 0);   // raw blank logit, row rbase
    const float xblk1 = lane_bcast(xb0.x, 0);   // raw blank logit, row rbase+1

#pragma unroll
    for (int rr = 0; rr < 2; ++rr) {
        const int r = rbase + rr;
        const int b = r & (B - 1), t = r >> 6;    // r = t*B + b
        const float* rw = rows[w][rr];
        const int lab_len = label_lens[b];
        const int off     = offsets[b];
        const float ubk   = rw[0];
        const float rub   = __builtin_amdgcn_rcpf(ubk);
        const int j0 = 4 * lane;
        float q0 = (j0 + 0 < lab_len) ? rw[labels[min(off + j0 + 0, B * L - 1)]] * rub : 1.f;
        float q1 = (j0 + 1 < lab_len) ? rw[labels[min(off + j0 + 1, B * L - 1)]] * rub : 1.f;
        float q2 = (j0 + 2 < lab_len) ? rw[labels[min(off + j0 + 2, B * L - 1)]] * rub : 1.f;
        float q3 = (j0 + 3 < lab_len) ? rw[labels[min(off + j0 + 3, B * L - 1)]] * rub : 1.f;
        ushort4 hv = {f2bf(q0), f2bf(q1), f2bf(q2), f2bf(q3)};
        ((ushort4*)packedR)[(size_t)(b * T + t) * 64 + lane] = hv;
        if (lane == 0) {
            lse_rows[b * T + t] = __logf(rr ? sb : sa);
            blankU[b * T + t]   = ubk;
            logub[b * T + t]    = rr ? xblk1 : xblk0;   // exact log u_blank
        }
    }
}

// ---------------------------------------------------------------------------
// Fwd/bwd linear-space CTC scan, all-VALU steps, named-scalar chunk buffers,
// RATIO form (see ws-layout comment). Even states: 1 add. Odd: add+fma+mul.
// No readlane, no blank traffic in the loop. Triple-buffered chunk prefetch
// issued 2 chunk-computes ahead; rescale every 8 steps (growth <= ~e^48).
// ---------------------------------------------------------------------------
__global__ __launch_bounds__(128, 1) void ctc_kernel(
    const int* __restrict__ labels, const int* __restrict__ act_lens,
    const int* __restrict__ label_lens, const int* __restrict__ offsets,
    const float* __restrict__ lse_rows, const unsigned short* __restrict__ packedR,
    const float* __restrict__ blankU, const float* __restrict__ logub,
    float* __restrict__ out)
{
    __shared__ float sbr[S];
    __shared__ float s_accb;

    const int b    = blockIdx.x;
    const int wave = threadIdx.x >> 6;
    const int lane = threadIdx.x & 63;
    const int lab_len = label_lens[b];
    const int a_len   = act_lens[b];
    const int th      = (a_len - 1) >> 1;
    const int thp1    = th + 1;
    const int off     = offsets[b];
    const size_t rowbase = (size_t)b * T;

    int li0 = 4 * lane;
    int eprev = (li0 - 1 >= 0 && li0 - 1 < lab_len) ? labels[min(off + li0 - 1, B * L - 1)] : 0;
    int enext = (li0 + 4 < lab_len) ? labels[min(off + li0 + 4, B * L - 1)] : 0;
    int e0 = (li0 + 0 < lab_len) ? labels[min(off + li0 + 0, B * L - 1)] : 0;
    int e1 = (li0 + 1 < lab_len) ? labels[min(off + li0 + 1, B * L - 1)] : 0;
    int e2 = (li0 + 2 < lab_len) ? labels[min(off + li0 + 2, B * L - 1)] : 0;
    int e3 = (li0 + 3 < lab_len) ? labels[min(off + li0 + 3, B * L - 1)] : 0;

    // skip-allow flags for odd states 8l+1,3,5,7 (same for fwd & bwd mappings)
    const float aF0 = (8 * lane + 1 >= 2 && e0 != 0 && e0 != eprev) ? 1.f : 0.f;
    const float aF1 = (e1 != 0 && e1 != e0) ? 1.f : 0.f;
    const float aF2 = (e2 != 0 && e2 != e1) ? 1.f : 0.f;
    const float aF3 = (e3 != 0 && e3 != e2) ? 1.f : 0.f;
    const float aB0 = aF1, aB1 = aF2, aB2 = aF3;
    const float aB3 = (enext != 0 && enext != e3) ? 1.f : 0.f;

    float A0 = 0.f, A1 = 0.f, A2 = 0.f, A3 = 0.f, A4 = 0.f,
          A5 = 0.f, A6 = 0.f, A7 = 0.f, A8 = 0.f;
    float acc = 0.f, sls = 0.f, slog = 0.f;

    // NAMED scalar chunk buffers (no arrays -> no scratch, ever)
    uint2 a_0,a_1,a_2,a_3,a_4,a_5,a_6,a_7,a_8,a_9,a_10,a_11,a_12,a_13,a_14,a_15;
    uint2 b_0,b_1,b_2,b_3,b_4,b_5,b_6,b_7,b_8,b_9,b_10,b_11,b_12,b_13,b_14,b_15;
    uint2 c_0,c_1,c_2,c_3,c_4,c_5,c_6,c_7,c_8,c_9,c_10,c_11,c_12,c_13,c_14,c_15;

#define PINV(x) asm volatile("" : "+v"(x))
#define APPLY16(M, P) M(P,0) M(P,1) M(P,2) M(P,3) M(P,4) M(P,5) M(P,6) M(P,7) \
                      M(P,8) M(P,9) M(P,10) M(P,11) M(P,12) M(P,13) M(P,14) M(P,15)

#define LD1(P, I) P##_##I = gp_[(I) * 64 + lane];
#define LOADCH(P, TLO) do {                                                   \
        const int tl_ = min(max((int)(TLO), 0), T - C);                       \
        const uint2* gp_ = (const uint2*)(packedR + (rowbase + tl_) * 256);   \
        APPLY16(LD1, P)                                                       \
    } while (0)

#define PIN1(P, I) PINV(P##_##I.x); PINV(P##_##I.y);
#define PINCH(P) do { APPLY16(PIN1, P) } while (0)

#define RESCALE() do {                                                        \
        float m_ = fmaxf(A8, A0); m_ = fmaxf(m_, A1); m_ = fmaxf(m_, A2);     \
        m_ = fmaxf(m_, A3); m_ = fmaxf(m_, A4); m_ = fmaxf(m_, A5);           \
        m_ = fmaxf(m_, A6); m_ = fmaxf(m_, A7);                               \
        DPPMAX_LADDER(m_);                                                    \
        m_ = lane_bcast(m_, 63);                                              \
        m_ = fmaxf(m_, 1e-30f);                                               \
        float inv_ = __builtin_amdgcn_rcpf(m_);                               \
        acc += __logf(m_);                                                    \
        A0 *= inv_; A1 *= inv_; A2 *= inv_; A3 *= inv_; A4 *= inv_;           \
        A5 *= inv_; A6 *= inv_; A7 *= inv_; A8 *= inv_;                       \
    } while (0)

    // fwd (ratio form): lane holds states 8l..8l+7, A8 = state 512 on lane 63
#define STEPF_CORE(HX, HY) do {                                               \
        const unsigned hx_ = (HX), hy_ = (HY);                                \
        const float u0_ = __uint_as_float(hx_ << 16);                         \
        const float u1_ = __uint_as_float(hx_ & 0xffff0000u);                 \
        const float u2_ = __uint_as_float(hy_ << 16);                         \
        const float u3_ = __uint_as_float(hy_ & 0xffff0000u);                 \
        const float pA7_ = dpp_shr1z(A7);                                     \
        A8 = A8 + A7;                                                         \
        A7 = u3_ * fmaf(aF3, A5, A7 + A6);                                    \
        A6 = A6 + A5;                                                         \
        A5 = u2_ * fmaf(aF2, A3, A5 + A4);                                    \
        A4 = A4 + A3;                                                         \
        A3 = u1_ * fmaf(aF1, A1, A3 + A2);                                    \
        A2 = A2 + A1;                                                         \
        A1 = u0_ * fmaf(aF0, pA7_, A1 + A0);                                  \
        A0 = A0 + pA7_;                                                       \
    } while (0)

    // bwd (ratio form): lane holds states 8l+1..8l+8, A8 = state 0 on lane 0
#define STEPB_CORE(HX, HY) do {                                               \
        const unsigned hx_ = (HX), hy_ = (HY);                                \
        const float u0_ = __uint_as_float(hx_ << 16);                         \
        const float u1_ = __uint_as_float(hx_ & 0xffff0000u);                 \
        const float u2_ = __uint_as_float(hy_ << 16);                         \
        const float u3_ = __uint_as_float(hy_ & 0xffff0000u);                 \
        const float nC0_ = dpp_shl1z(A0);                                     \
        A8 = A8 + A0;                                                         \
        A0 = u0_ * fmaf(aB0, A2, A0 + A1);                                    \
        A1 = A1 + A2;                                                         \
        A2 = u1_ * fmaf(aB1, A4, A2 + A3);                                    \
        A3 = A3 + A4;                                                         \
        A4 = u2_ * fmaf(aB2, A6, A4 + A5);                                    \
        A5 = A5 + A6;                                                         \
        A6 = u3_ * fmaf(aB3, nC0_, A6 + A7);                                  \
        A7 = A7 + nC0_;                                                       \
    } while (0)

#define SF(P, I)  STEPF_CORE(P##_##I.x, P##_##I.y);
#define SB(P, I)  STEPB_CORE(P##_##I.x, P##_##I.y);
#define SFG(P, I, TLO) if ((TLO) + (I) <= th)   { SF(P, I) }
#define SBG(P, I, TLO) if ((TLO) + (I) >= thp1) { SB(P, I) }

#define DOF16(P) do {                                                         \
        SF(P,0) SF(P,1) SF(P,2) SF(P,3) SF(P,4) SF(P,5) SF(P,6) SF(P,7)       \
        RESCALE();                                                            \
        SF(P,8) SF(P,9) SF(P,10) SF(P,11) SF(P,12) SF(P,13) SF(P,14) SF(P,15) \
        RESCALE();                                                            \
    } while (0)
#define DOFPART(P, TLO) do {                                                  \
        SFG(P,0,TLO) SFG(P,1,TLO) SFG(P,2,TLO) SFG(P,3,TLO)                   \
        SFG(P,4,TLO) SFG(P,5,TLO) SFG(P,6,TLO) SFG(P,7,TLO)                   \
        RESCALE();                                                            \
        SFG(P,8,TLO) SFG(P,9,TLO) SFG(P,10,TLO) SFG(P,11,TLO)                 \
        SFG(P,12,TLO) SFG(P,13,TLO) SFG(P,14,TLO) SFG(P,15,TLO)               \
        RESCALE();                                                            \
    } while (0)
#define DOB16(P) do {                                                         \
        SB(P,15) SB(P,14) SB(P,13) SB(P,12) SB(P,11) SB(P,10) SB(P,9) SB(P,8) \
        RESCALE();                                                            \
        SB(P,7) SB(P,6) SB(P,5) SB(P,4) SB(P,3) SB(P,2) SB(P,1) SB(P,0)       \
        RESCALE();                                                            \
    } while (0)
#define DOBPART(P, TLO) do {                                                  \
        SBG(P,15,TLO) SBG(P,14,TLO) SBG(P,13,TLO) SBG(P,12,TLO)               \
        SBG(P,11,TLO) SBG(P,10,TLO) SBG(P,9,TLO) SBG(P,8,TLO)                 \
        RESCALE();                                                            \
        SBG(P,7,TLO) SBG(P,6,TLO) SBG(P,5,TLO) SBG(P,4,TLO)                   \
        SBG(P,3,TLO) SBG(P,2,TLO) SBG(P,1,TLO) SBG(P,0,TLO)                   \
        RESCALE();                                                            \
    } while (0)

#define STEP_DIRECT(WHICH, TT) do {                                           \
        uint2 hvd_ = ((const uint2*)(packedR + (rowbase + (TT)) * 256))[lane];\
        WHICH(hvd_.x, hvd_.y);                                                \
    } while (0)

    if (wave == 0) {
        if (lane == 0) {
            A0 = blankU[rowbase];                   // alpha0(0) = u_blank(0)
            A1 = __uint_as_float(((unsigned)packedR[rowbase * 256]) << 16) * A0;
        }

        if (th >= 1) {
            const int nst   = th;           // steps t = 1..th, chunk c: tlo=1+16c
            const int nc    = (nst + C - 1) / C;
            const int nfull = nst / C;
            LOADCH(a, 1);
            LOADCH(b, 1 + C);
            LOADCH(c, 1 + 2 * C);

            // lse + interior-logub sums overlap the first chunk's load latency
            if (a_len == T) {               // fast path: vector loads + DPP ladder
                const f32x4* lp = (const f32x4*)(lse_rows + rowbase);
                const f32x4* gp = (const f32x4*)(logub + rowbase);
                f32x4 s0 = lp[lane], s1 = lp[lane + 64],
                      s2 = lp[lane + 128], s3 = lp[lane + 192];
                f32x4 g0 = gp[lane], g1 = gp[lane + 64],
                      g2 = gp[lane + 128], g3 = gp[lane + 192];
                float s = s0.x+s0.y+s0.z+s0.w + s1.x+s1.y+s1.z+s1.w
                        + s2.x+s2.y+s2.z+s2.w + s3.x+s3.y+s3.z+s3.w;
                float g = g0.x+g0.y+g0.z+g0.w + g1.x+g1.y+g1.z+g1.w
                        + g2.x+g2.y+g2.z+g2.w + g3.x+g3.y+g3.z+g3.w;
                DPPADD_LADDER(s); DPPADD_LADDER(g);
                sls  = lane_bcast(s, 63);
                slog = lane_bcast(g, 63) - logub[rowbase] - logub[rowbase + T - 1];
            } else {
                float g = 0.f;
                for (int t = lane; t < a_len; t += 64) {
                    sls += lse_rows[rowbase + t];
                    if (t >= 1 && t <= a_len - 2) g += logub[rowbase + t];
                }
#pragma unroll
                for (int o = 32; o; o >>= 1) {
                    sls += __shfl_xor(sls, o, 64);
                    g   += __shfl_xor(g, o, 64);
                }
                slog = g;
            }

            int cc = 0;
            for (; cc + 3 <= nfull; cc += 3) {
                PINCH(a); DOF16(a); LOADCH(a, 1 + C * (cc + 3));
                PINCH(b); DOF16(b); LOADCH(b, 1 + C * (cc + 4));
                PINCH(c); DOF16(c); LOADCH(c, 1 + C * (cc + 5));
            }
            const int rem = nfull - cc;
            if (rem == 0) {
                if (nc > nfull) { PINCH(a); DOFPART(a, 1 + C * cc); }
            } else if (rem == 1) {
                PINCH(a); DOF16(a);
                if (nc > nfull) { PINCH(b); DOFPART(b, 1 + C * (cc + 1)); }
            } else {
                PINCH(a); DOF16(a);
                PINCH(b); DOF16(b);
                if (nc > nfull) { PINCH(c); DOFPART(c, 1 + C * (cc + 2)); }
            }
        } else {
            float g = 0.f;
            for (int t = lane; t < a_len; t += 64) {
                sls += lse_rows[rowbase + t];
                if (t >= 1 && t <= a_len - 2) g += logub[rowbase + t];
            }
#pragma unroll
            for (int o = 32; o; o >>= 1) {
                sls += __shfl_xor(sls, o, 64);
                g   += __shfl_xor(g, o, 64);
            }
            slog = g;
        }
    } else {
        const int send = 2 * lab_len;
        {
            size_t rl = rowbase + (a_len - 1);
            float ubl = blankU[rl];
            float ue  = (lab_len > 0)
                      ? __uint_as_float(((unsigned)packedR[rl * 256 + (lab_len - 1)]) << 16) * ubl
                      : 0.f;
            int s0 = 8 * lane + 1;                  // states s0..s0+7
            A0 = (s0 + 0 == send) ? ubl : ((s0 + 0 == send - 1) ? ue : 0.f);
            A1 = (s0 + 1 == send) ? ubl : ((s0 + 1 == send - 1) ? ue : 0.f);
            A2 = (s0 + 2 == send) ? ubl : ((s0 + 2 == send - 1) ? ue : 0.f);
            A3 = (s0 + 3 == send) ? ubl : ((s0 + 3 == send - 1) ? ue : 0.f);
            A4 = (s0 + 4 == send) ? ubl : ((s0 + 4 == send - 1) ? ue : 0.f);
            A5 = (s0 + 5 == send) ? ubl : ((s0 + 5 == send - 1) ? ue : 0.f);
            A6 = (s0 + 6 == send) ? ubl : ((s0 + 6 == send - 1) ? ue : 0.f);
            A7 = (s0 + 7 == send) ? ubl : ((s0 + 7 == send - 1) ? ue : 0.f);
            A8 = (send == 0) ? ubl : 0.f;           // state 0 (lane 0's only used)
        }

        const int nstB = a_len - 2 - th;            // steps t = a_len-2 .. th+1
        if (nstB > 0 && a_len >= 17) {
            // chunk c: tlo = a_len-17-16c, rows tlo..tlo+15 = steps (desc)
            const int nc    = (nstB + C - 1) / C;
            const int nfull = nstB / C;
            LOADCH(a, a_len - 17);
            LOADCH(b, a_len - 17 - C);
            LOADCH(c, a_len - 17 - 2 * C);
            int cc = 0;
            for (; cc + 3 <= nfull; cc += 3) {
                PINCH(a); DOB16(a); LOADCH(a, a_len - 17 - C * (cc + 3));
                PINCH(b); DOB16(b); LOADCH(b, a_len - 17 - C * (cc + 4));
                PINCH(c); DOB16(c); LOADCH(c, a_len - 17 - C * (cc + 5));
            }
            const int rem = nfull - cc;
            if (rem == 0) {
                if (nc > nfull) { PINCH(a); DOBPART(a, a_len - 17 - C * cc); }
            } else if (rem == 1) {
                PINCH(a); DOB16(a);
                if (nc > nfull) { PINCH(b); DOBPART(b, a_len - 17 - C * (cc + 1)); }
            } else {
                PINCH(a); DOB16(a);
                PINCH(b); DOB16(b);
                if (nc > nfull) { PINCH(c); DOBPART(c, a_len - 17 - C * (cc + 2)); }
            }
        } else if (nstB > 0) {                      // tiny a_len fallback
            for (int t = a_len - 2; t >= thp1; --t) {
                STEP_DIRECT(STEPB_CORE, t);
                if (((a_len - 2 - t) & 7) == 7) RESCALE();
            }
        }

        {   // bracket W(s) = B(s) + B(s+1) + allow(s+2)*B(s+2), B = beta'_{th+1}
            float nC0 = dpp_shl1z(A0);
            float w1 = fmaf(aB0, A2, A0 + A1);      // s = 8l+1
            float w2 = A1 + A2;                     // s = 8l+2
            float w3 = fmaf(aB1, A4, A2 + A3);      // s = 8l+3
            float w4 = A3 + A4;                     // s = 8l+4
            float w5 = fmaf(aB2, A6, A4 + A5);      // s = 8l+5
            float w6 = A5 + A6;                     // s = 8l+6
            float w7 = fmaf(aB3, nC0, A6 + A7);     // s = 8l+7
            float w8 = A7 + nC0;                    // s = 8l+8
            int sB = 8 * lane + 1;
            sbr[sB + 0] = w1; sbr[sB + 1] = w2; sbr[sB + 2] = w3; sbr[sB + 3] = w4;
            sbr[sB + 4] = w5; sbr[sB + 5] = w6; sbr[sB + 6] = w7; sbr[sB + 7] = w8;
            if (lane == 0) sbr[0] = A8 + A0;        // W(0) = B(0) + B(1)
            if (lane == 0) s_accb = acc;
        }
    }
    __syncthreads();
    if (wave == 0) {
        // LOG-space junction (linear dot of the two independently-rescaled
        // sides underflows fp32)
        int s0 = 8 * lane;
        float p0 = __logf(fmaxf(A0, 1e-37f)) + __logf(fmaxf(sbr[s0 + 0], 1e-37f));
        float p1 = __logf(fmaxf(A1, 1e-37f)) + __logf(fmaxf(sbr[s0 + 1], 1e-37f));
        float p2 = __logf(fmaxf(A2, 1e-37f)) + __logf(fmaxf(sbr[s0 + 2], 1e-37f));
        float p3 = __logf(fmaxf(A3, 1e-37f)) + __logf(fmaxf(sbr[s0 + 3], 1e-37f));
        float p4 = __logf(fmaxf(A4, 1e-37f)) + __logf(fmaxf(sbr[s0 + 4], 1e-37f));
        float p5 = __logf(fmaxf(A5, 1e-37f)) + __logf(fmaxf(sbr[s0 + 5], 1e-37f));
        float p6 = __logf(fmaxf(A6, 1e-37f)) + __logf(fmaxf(sbr[s0 + 6], 1e-37f));
        float p7 = __logf(fmaxf(A7, 1e-37f)) + __logf(fmaxf(sbr[s0 + 7], 1e-37f));
        float p8 = -3.0e38f;
        if (lane == 63) p8 = __logf(fmaxf(A8, 1e-37f)) + __logf(fmaxf(sbr[512], 1e-37f));
        float pmax = fmaxf(fmaxf(fmaxf(p0, p1), fmaxf(p2, p3)),
                           fmaxf(fmaxf(p4, p5), fmaxf(p6, p7)));
        pmax = fmaxf(pmax, p8);
        DPPMAX_LADDER(pmax);
        pmax = lane_bcast(pmax, 63);
        float dot = __expf(p0 - pmax) + __expf(p1 - pmax) + __expf(p2 - pmax)
                  + __expf(p3 - pmax) + __expf(p4 - pmax) + __expf(p5 - pmax)
                  + __expf(p6 - pmax) + __expf(p7 - pmax);
        if (lane == 63) dot += __expf(p8 - pmax);
        DPPADD_LADDER(dot);
        dot = lane_bcast(dot, 63);
        if (lane == 0) {
            float loss = sls - slog - acc - s_accb - (pmax + __logf(dot));
            atomicAdd(out, loss);
        }
    }
#undef PINV
#undef APPLY16
#undef LD1
#undef LOADCH
#undef PIN1
#undef PINCH
#undef RESCALE
#undef STEPF_CORE
#undef STEPB_CORE
#undef SF
#undef SB
#undef SFG
#undef SBG
#undef DOF16
#undef DOFPART
#undef DOB16
#undef DOBPART
#undef STEP_DIRECT
}

extern "C" void kernel_launch(void* const* d_in, const int* in_sizes, int n_in,
                              void* d_out, int out_size, void* d_ws, size_t ws_size,
                              hipStream_t stream) {
    const float* acts       = (const float*)d_in[0];
    const int*   labels     = (const int*)d_in[1];
    const int*   act_lens   = (const int*)d_in[2];
    const int*   label_lens = (const int*)d_in[3];
    float*       out        = (float*)d_out;

    float*          lse_rows = (float*)d_ws;
    float*          blankU   = (float*)((char*)d_ws + (size_t)T * B * 4);
    int*            offsets  = (int*)  ((char*)d_ws + (size_t)2 * T * B * 4);
    float*          logub    = (float*)((char*)d_ws + (size_t)3 * T * B * 4);
    unsigned short* packedR  = (unsigned short*)((char*)d_ws + (1u << 20));

    hipMemsetAsync(d_out, 0, sizeof(float), stream);

    offsets_kernel<<<1, 64, 0, stream>>>(label_lens, offsets);
    setup_kernel<<<T * B / 8, 256, 0, stream>>>(
        acts, labels, label_lens, offsets, lse_rows, packedR, blankU, logub);
    ctc_kernel<<<B, 128, 0, stream>>>(
        labels, act_lens, label_lens, offsets, lse_rows, packedR, blankU, logub, out);
}